// Round 3
// baseline (4306.212 us; speedup 1.0000x reference)
//
#include <hip/hip_runtime.h>
#include <stdint.h>

// ---- types ----
typedef __attribute__((ext_vector_type(8))) short short8;   // 8 bf16 = 4 VGPR (MFMA A/B frag)
typedef __attribute__((ext_vector_type(4))) short short4v;  // 4 bf16 = 8B
typedef __attribute__((ext_vector_type(4))) float f32x4;    // MFMA C/D frag
typedef __attribute__((ext_vector_type(4))) unsigned int u32x4;
typedef __attribute__((ext_vector_type(4))) int i32x4;
typedef __attribute__((ext_vector_type(2))) unsigned long long u64x2;

// ---- bf16 helpers (manual RNE) ----
__device__ inline unsigned short f2bf(float f) {
  unsigned int u = __builtin_bit_cast(unsigned int, f);
  u += 0x7fffu + ((u >> 16) & 1u);
  return (unsigned short)(u >> 16);
}
__device__ inline float bf2f(unsigned short s) {
  return __builtin_bit_cast(float, (unsigned int)s << 16);
}

// sentinel = bf16 0x7F7F (=3.39e38). |h|<1 strictly -> cannot collide with data.
// stale64(v) != 0 iff any 16-bit lane of v equals 0x7F7F.
__device__ inline unsigned long long stale64(unsigned long long v) {
  unsigned long long x = v ^ 0x7f7f7f7f7f7f7f7full;
  return (x - 0x0001000100010001ull) & ~x & 0x8000800080008000ull;
}

// Problem constants: B=32, T=512, D=H=1024, 4H=4096, M = T*B = 16384
// gx layout: [t][b][n] bf16, n = permuted gate-row (4*j + gate)
// hs layout: [t][b][j]  bf16

// ---- x: [B][T][D] f32  ->  xbf: [m = t*32+b][d] bf16 ----
__global__ __launch_bounds__(256) void cvt_x_kernel(const float* __restrict__ x,
                                                    short* __restrict__ xbf) {
  const int total = (16384 * 1024) / 4;
  for (int i = blockIdx.x * blockDim.x + threadIdx.x; i < total;
       i += gridDim.x * blockDim.x) {
    int d4 = i & 255;
    int m  = i >> 8;
    int t = m >> 5, b = m & 31;
    float4 v = *(const float4*)(x + ((size_t)b * 512 + t) * 1024 + (size_t)d4 * 4);
    short4v o;
    o.x = (short)f2bf(v.x); o.y = (short)f2bf(v.y);
    o.z = (short)f2bf(v.z); o.w = (short)f2bf(v.w);
    *(short4v*)(xbf + (size_t)m * 1024 + d4 * 4) = o;
  }
}

// ---- W: [4096][1024] f32 -> Wp: gate-interleaved rows, bf16. ----
__global__ __launch_bounds__(256) void cvt_w_kernel(const float* __restrict__ W,
                                                    short* __restrict__ Wp) {
  const int total = (4096 * 1024) / 4;
  for (int i = blockIdx.x * blockDim.x + threadIdx.x; i < total;
       i += gridDim.x * blockDim.x) {
    int k4 = i & 255;
    int n  = i >> 8;
    int g = n & 3, j = n >> 2;
    float4 v = *(const float4*)(W + ((size_t)g * 1024 + j) * 1024 + (size_t)k4 * 4);
    short4v o;
    o.x = (short)f2bf(v.x); o.y = (short)f2bf(v.y);
    o.z = (short)f2bf(v.z); o.w = (short)f2bf(v.w);
    *(short4v*)(Wp + (size_t)n * 1024 + k4 * 4) = o;
  }
}

// ---- bias permute (stays f32) ----
__global__ __launch_bounds__(256) void cvt_b_kernel(const float* __restrict__ b,
                                                    float* __restrict__ bp) {
  int n = blockIdx.x * blockDim.x + threadIdx.x;
  if (n < 4096) bp[n] = b[(n & 3) * 1024 + (n >> 2)];
}

// ---- bf16 MFMA GEMM:  C[t][b][n] = sum_k A[n][k] * Bm[m=t*32+b][k] ----
__global__ __launch_bounds__(256) void gemm_bt(const short* __restrict__ A,
                                               const short* __restrict__ Bm,
                                               short* __restrict__ C) {
  const int n0 = blockIdx.x * 128;
  const int m0 = blockIdx.y * 128;
  const int tid = threadIdx.x;
  const int lane = tid & 63, wid = tid >> 6;
  const int wr = wid >> 1, wc = wid & 1;
  const int fr = lane & 15, fq = lane >> 4;

  __shared__ __align__(16) short As[128 * 32];
  __shared__ __align__(16) short Bs[128 * 32];

  f32x4 acc[4][4];
#pragma unroll
  for (int i = 0; i < 4; i++)
#pragma unroll
    for (int j = 0; j < 4; j++) acc[i][j] = (f32x4){0.f, 0.f, 0.f, 0.f};

  for (int kt = 0; kt < 1024; kt += 32) {
#pragma unroll
    for (int s = 0; s < 2; s++) {
      int c = tid + s * 256;
      int row = c >> 2;
      int off = (c & 3) * 8;
      *(u32x4*)&As[row * 32 + off] =
          *(const u32x4*)(A + (size_t)(n0 + row) * 1024 + kt + off);
      *(u32x4*)&Bs[row * 32 + off] =
          *(const u32x4*)(Bm + (size_t)(m0 + row) * 1024 + kt + off);
    }
    __syncthreads();
    short8 af[4], bf[4];
#pragma unroll
    for (int i = 0; i < 4; i++)
      af[i] = *(const short8*)&As[(wr * 64 + i * 16 + fr) * 32 + fq * 8];
#pragma unroll
    for (int j = 0; j < 4; j++)
      bf[j] = *(const short8*)&Bs[(wc * 64 + j * 16 + fr) * 32 + fq * 8];
#pragma unroll
    for (int i = 0; i < 4; i++)
#pragma unroll
      for (int j = 0; j < 4; j++)
        acc[i][j] = __builtin_amdgcn_mfma_f32_16x16x32_bf16(af[i], bf[j], acc[i][j], 0, 0, 0);
    __syncthreads();
  }

#pragma unroll
  for (int i = 0; i < 4; i++) {
#pragma unroll
    for (int j = 0; j < 4; j++) {
      int nq = n0 + wr * 64 + i * 16 + fq * 4;
      int m = m0 + wc * 64 + j * 16 + fr;
      int t = m >> 5, b = m & 31;
      unsigned long long pk = 0;
#pragma unroll
      for (int r = 0; r < 4; r++)
        pk |= (unsigned long long)f2bf(acc[i][j][r]) << (16 * r);
      *(unsigned long long*)&C[(size_t)t * 131072 + (size_t)b * 4096 + nq] = pk;
    }
  }
}

// Opportunistic pull + verify, with cheap 8B-probe spin on failure.
// L1 variant: 8 chunks per thread. Uses locals soff[8], widx[8], ibw.
#define PULL8_VERIFY(HBP)                                                     \
  do {                                                                        \
    i32x4 r0, r1, r2, r3, r4, r5, r6, r7;                                     \
    while (true) {                                                            \
      asm volatile(                                                           \
          "global_load_dwordx4 %0, %8, %16 sc0 sc1\n\t"                       \
          "global_load_dwordx4 %1, %9, %16 sc0 sc1\n\t"                       \
          "global_load_dwordx4 %2, %10, %16 sc0 sc1\n\t"                      \
          "global_load_dwordx4 %3, %11, %16 sc0 sc1\n\t"                      \
          "global_load_dwordx4 %4, %12, %16 sc0 sc1\n\t"                      \
          "global_load_dwordx4 %5, %13, %16 sc0 sc1\n\t"                      \
          "global_load_dwordx4 %6, %14, %16 sc0 sc1\n\t"                      \
          "global_load_dwordx4 %7, %15, %16 sc0 sc1\n\t"                      \
          "s_waitcnt vmcnt(0)"                                                \
          : "=&v"(r0), "=&v"(r1), "=&v"(r2), "=&v"(r3), "=&v"(r4),            \
            "=&v"(r5), "=&v"(r6), "=&v"(r7)                                   \
          : "v"(soff[0]), "v"(soff[1]), "v"(soff[2]), "v"(soff[3]),           \
            "v"(soff[4]), "v"(soff[5]), "v"(soff[6]), "v"(soff[7]),           \
            "s"(HBP)                                                          \
          : "memory");                                                        \
      u64x2 q0 = __builtin_bit_cast(u64x2, r0), q1 = __builtin_bit_cast(u64x2, r1); \
      u64x2 q2 = __builtin_bit_cast(u64x2, r2), q3 = __builtin_bit_cast(u64x2, r3); \
      u64x2 q4 = __builtin_bit_cast(u64x2, r4), q5 = __builtin_bit_cast(u64x2, r5); \
      u64x2 q6 = __builtin_bit_cast(u64x2, r6), q7 = __builtin_bit_cast(u64x2, r7); \
      unsigned long long bad =                                                \
          stale64(q0.x) | stale64(q0.y) | stale64(q1.x) | stale64(q1.y) |     \
          stale64(q2.x) | stale64(q2.y) | stale64(q3.x) | stale64(q3.y) |     \
          stale64(q4.x) | stale64(q4.y) | stale64(q5.x) | stale64(q5.y) |     \
          stale64(q6.x) | stale64(q6.y) | stale64(q7.x) | stale64(q7.y);      \
      if (!bad) break;                                                        \
      unsigned long long p0, p1, p2, p3, p4, p5, p6, p7;                      \
      do {                                                                    \
        asm volatile(                                                         \
            "global_load_dwordx2 %0, %8, %16 sc0 sc1\n\t"                     \
            "global_load_dwordx2 %1, %9, %16 sc0 sc1\n\t"                     \
            "global_load_dwordx2 %2, %10, %16 sc0 sc1\n\t"                    \
            "global_load_dwordx2 %3, %11, %16 sc0 sc1\n\t"                    \
            "global_load_dwordx2 %4, %12, %16 sc0 sc1\n\t"                    \
            "global_load_dwordx2 %5, %13, %16 sc0 sc1\n\t"                    \
            "global_load_dwordx2 %6, %14, %16 sc0 sc1\n\t"                    \
            "global_load_dwordx2 %7, %15, %16 sc0 sc1\n\t"                    \
            "s_waitcnt vmcnt(0)"                                              \
            : "=&v"(p0), "=&v"(p1), "=&v"(p2), "=&v"(p3), "=&v"(p4),          \
              "=&v"(p5), "=&v"(p6), "=&v"(p7)                                 \
            : "v"(soff[0]), "v"(soff[1]), "v"(soff[2]), "v"(soff[3]),         \
              "v"(soff[4]), "v"(soff[5]), "v"(soff[6]), "v"(soff[7]),         \
              "s"(HBP)                                                        \
            : "memory");                                                      \
      } while (stale64(p0) | stale64(p1) | stale64(p2) | stale64(p3) |        \
               stale64(p4) | stale64(p5) | stale64(p6) | stale64(p7));        \
    }                                                                         \
    *(i32x4*)&ibw[widx[0]] = r0;                                              \
    *(i32x4*)&ibw[widx[1]] = r1;                                              \
    *(i32x4*)&ibw[widx[2]] = r2;                                              \
    *(i32x4*)&ibw[widx[3]] = r3;                                              \
    *(i32x4*)&ibw[widx[4]] = r4;                                              \
    *(i32x4*)&ibw[widx[5]] = r5;                                              \
    *(i32x4*)&ibw[widx[6]] = r6;                                              \
    *(i32x4*)&ibw[widx[7]] = r7;                                              \
  } while (0)

// ---- fused 2-layer pipelined LSTM ----
// grid = 192 WGs x 512 threads, all resident (1 WG/CU), no inter-group cycles.
//   WGs   0..63 : layer-0 recurrence. WG owns 128 gate-rows x 16 batches.
//   WGs 64..191 : layer-1. WG owns 64 gate-rows x 16 batches; waves 0-3 hold
//                 Whh1 (consume h1[t-1] image), waves 4-7 hold Wih1 (consume
//                 h0[t] image); partial gate sums meet in an LDS red buffer.
// Handoff: PROVEN sentinel-in-data protocol (one hop: data write IS signal).
// New vs R1: opportunistic pull + 8B-probe spin; LDS double-buffered images
// (tail barrier dropped); per-lane 2B h stores (no shfl pack).
__global__ __launch_bounds__(512, 1) void lstm_fused(
    const short* __restrict__ gx0, const short* __restrict__ whh0,
    const float* __restrict__ b0p, const short* __restrict__ wih1,
    const short* __restrict__ whh1, const float* __restrict__ b1p,
    short* __restrict__ hs0, short* __restrict__ hs1,
    float* __restrict__ out, float* __restrict__ hn, float* __restrict__ cn) {
  const int tid = threadIdx.x;
  const int lane = tid & 63, w = tid >> 6;
  const int fr = lane & 15, fq = lane >> 4;

  // double-buffered h images: L0 uses first 16K shorts of each buffer;
  // L1 uses both 16K halves (mw split). 128KB total.
  __shared__ __align__(16) short img[2][32768];
  __shared__ __align__(16) float red[2][1024];   // L1 k-partial exchange, dbuf

  if (blockIdx.x < 64) {
    // ================= layer 0: 128 gate-rows x 16 batches =================
    const int rg = (int)blockIdx.x >> 1, bg = (int)blockIdx.x & 1;
    const int n_base = rg * 128 + w * 16;
    const int b = bg * 16 + fr;
    const int j = rg * 32 + w * 4 + fq;  // h column this lane owns
    const int sw = fr & 7;

    const short* arow = whh0 + (size_t)(n_base + fr) * 1024 + fq * 8;
    short8 wreg[32];
#pragma unroll
    for (int kk = 0; kk < 32; kk++) wreg[kk] = *(const short8*)(arow + kk * 32);

    float bia[4];
#pragma unroll
    for (int r = 0; r < 4; r++) bia[r] = b0p[n_base + fq * 4 + r];

    // stage: 2048 16B chunks of the 32KB half-image over 512 threads (4 each)
    unsigned int soff[4];
    int widx[4];
#pragma unroll
    for (int i = 0; i < 4; i++) {
      int ch = tid + i * 512;
      soff[i] = (unsigned int)ch * 16;
      int bb = ch >> 7, cc = ch & 127;
      widx[i] = bb * 1024 + ((cc ^ (bb & 7)) << 3);
    }

    float cell = 0.f;
    for (int t = 0; t < 512; ++t) {
      unsigned long long gq = __builtin_nontemporal_load(
          (const unsigned long long*)(gx0 + (size_t)t * 131072 +
                                      (size_t)b * 4096 + n_base + fq * 4));

      if (t > 0) {
        const short* hbp = hs0 + (size_t)(t - 1) * 32768 + bg * 16384;
        short* ibw = img[t & 1];
        i32x4 r0, r1, r2, r3;
        while (true) {
          asm volatile(
              "global_load_dwordx4 %0, %4, %8 sc0 sc1\n\t"
              "global_load_dwordx4 %1, %5, %8 sc0 sc1\n\t"
              "global_load_dwordx4 %2, %6, %8 sc0 sc1\n\t"
              "global_load_dwordx4 %3, %7, %8 sc0 sc1\n\t"
              "s_waitcnt vmcnt(0)"
              : "=&v"(r0), "=&v"(r1), "=&v"(r2), "=&v"(r3)
              : "v"(soff[0]), "v"(soff[1]), "v"(soff[2]), "v"(soff[3]),
                "s"(hbp)
              : "memory");
          u64x2 q0 = __builtin_bit_cast(u64x2, r0);
          u64x2 q1 = __builtin_bit_cast(u64x2, r1);
          u64x2 q2 = __builtin_bit_cast(u64x2, r2);
          u64x2 q3 = __builtin_bit_cast(u64x2, r3);
          unsigned long long bad =
              stale64(q0.x) | stale64(q0.y) | stale64(q1.x) | stale64(q1.y) |
              stale64(q2.x) | stale64(q2.y) | stale64(q3.x) | stale64(q3.y);
          if (!bad) break;
          unsigned long long p0, p1, p2, p3;
          do {
            asm volatile(
                "global_load_dwordx2 %0, %4, %8 sc0 sc1\n\t"
                "global_load_dwordx2 %1, %5, %8 sc0 sc1\n\t"
                "global_load_dwordx2 %2, %6, %8 sc0 sc1\n\t"
                "global_load_dwordx2 %3, %7, %8 sc0 sc1\n\t"
                "s_waitcnt vmcnt(0)"
                : "=&v"(p0), "=&v"(p1), "=&v"(p2), "=&v"(p3)
                : "v"(soff[0]), "v"(soff[1]), "v"(soff[2]), "v"(soff[3]),
                  "s"(hbp)
                : "memory");
          } while (stale64(p0) | stale64(p1) | stale64(p2) | stale64(p3));
        }
        *(i32x4*)&ibw[widx[0]] = r0;
        *(i32x4*)&ibw[widx[1]] = r1;
        *(i32x4*)&ibw[widx[2]] = r2;
        *(i32x4*)&ibw[widx[3]] = r3;
      }
      __syncthreads();  // image staged; (dbuf makes this the only barrier)

      f32x4 a0 = (f32x4){0.f,0.f,0.f,0.f}, a1 = (f32x4){0.f,0.f,0.f,0.f};
      f32x4 a2 = (f32x4){0.f,0.f,0.f,0.f}, a3 = (f32x4){0.f,0.f,0.f,0.f};
      if (t > 0) {
        const short* ibr = img[t & 1];
#pragma unroll
        for (int m = 0; m < 8; m++) {
          const int chb = fq + m * 16;
          short8 bv0 = *(const short8*)&ibr[fr * 1024 + (((chb + 0) ^ sw) << 3)];
          short8 bv1 = *(const short8*)&ibr[fr * 1024 + (((chb + 4) ^ sw) << 3)];
          short8 bv2 = *(const short8*)&ibr[fr * 1024 + (((chb + 8) ^ sw) << 3)];
          short8 bv3 = *(const short8*)&ibr[fr * 1024 + (((chb + 12) ^ sw) << 3)];
          a0 = __builtin_amdgcn_mfma_f32_16x16x32_bf16(wreg[4 * m + 0], bv0, a0, 0, 0, 0);
          a1 = __builtin_amdgcn_mfma_f32_16x16x32_bf16(wreg[4 * m + 1], bv1, a1, 0, 0, 0);
          a2 = __builtin_amdgcn_mfma_f32_16x16x32_bf16(wreg[4 * m + 2], bv2, a2, 0, 0, 0);
          a3 = __builtin_amdgcn_mfma_f32_16x16x32_bf16(wreg[4 * m + 3], bv3, a3, 0, 0, 0);
        }
      }

      float pre0 = (a0[0] + a1[0]) + (a2[0] + a3[0]) + bf2f((unsigned short)(gq & 0xFFFF)) + bia[0];
      float pre1 = (a0[1] + a1[1]) + (a2[1] + a3[1]) + bf2f((unsigned short)((gq >> 16) & 0xFFFF)) + bia[1];
      float pre2 = (a0[2] + a1[2]) + (a2[2] + a3[2]) + bf2f((unsigned short)((gq >> 32) & 0xFFFF)) + bia[2];
      float pre3 = (a0[3] + a1[3]) + (a2[3] + a3[3]) + bf2f((unsigned short)((gq >> 48) & 0xFFFF)) + bia[3];

      float iv = 1.f / (1.f + __expf(-pre0));
      float fv = 1.f / (1.f + __expf(-pre1));
      float gv = 2.f / (1.f + __expf(-2.f * pre2)) - 1.f;
      float ov = 1.f / (1.f + __expf(-pre3));
      cell = fv * cell + iv * gv;
      float h = ov * (2.f / (1.f + __expf(-2.f * cell)) - 1.f);

      // per-lane 2B store: each lane owns one (b, j) -> no shfl pack needed
      {
        const short* sb = hs0 + (size_t)t * 32768;
        unsigned int voff = (unsigned int)((b * 1024 + j) * 2);
        unsigned int hv = (unsigned int)f2bf(h);
        asm volatile("global_store_short %0, %1, %2 sc0 sc1"
                     :: "v"(voff), "v"(hv), "s"(sb) : "memory");
      }
      if (t == 511) {
        hn[b * 1024 + j] = h;
        cn[b * 1024 + j] = cell;
      }
      // no tail barrier: next step stages into img[(t+1)&1]
    }
  } else {
    // ================= layer 1: 64 gate-rows x 16 batches, dual-matrix =====
    const int idx = (int)blockIdx.x - 64;
    const int rg = idx >> 1, bg = idx & 1;
    const int wn = w & 3, mw = w >> 2;        // mw=0: Whh1/h1, mw=1: Wih1/h0
    const int n_base = rg * 64 + wn * 16;
    const int b = bg * 16 + fr;
    const int j = rg * 16 + wn * 4 + fq;
    const int sw = fr & 7;
    const int ib = mw << 14;                  // LDS image half (shorts)

    const short* wsrc = mw ? wih1 : whh1;
    const short* arow = wsrc + (size_t)(n_base + fr) * 1024 + fq * 8;
    short8 wreg[32];
#pragma unroll
    for (int kk = 0; kk < 32; kk++) wreg[kk] = *(const short8*)(arow + kk * 32);

    float bia[4];
#pragma unroll
    for (int r = 0; r < 4; r++) bia[r] = b1p[n_base + fq * 4 + r];

    // each 256-thread half stages its own 32KB image: 8 chunks/thread
    const int lt = tid & 255;
    unsigned int soff[8];
    int widx[8];
#pragma unroll
    for (int i = 0; i < 8; i++) {
      int ch = lt + i * 256;
      soff[i] = (unsigned int)ch * 16;
      int bb = ch >> 7, cc = ch & 127;
      widx[i] = ib + bb * 1024 + ((cc ^ (bb & 7)) << 3);
    }

    float cell = 0.f;
    for (int t = 0; t < 512; ++t) {
      short* ibw = img[t & 1];
      if (mw) {
        const short* hbp = hs0 + (size_t)t * 32768 + bg * 16384;
        PULL8_VERIFY(hbp);
      } else if (t > 0) {
        const short* hbp = hs1 + (size_t)(t - 1) * 32768 + bg * 16384;
        PULL8_VERIFY(hbp);
      }
      __syncthreads();  // #1: both images staged

      f32x4 a0 = (f32x4){0.f,0.f,0.f,0.f}, a1 = (f32x4){0.f,0.f,0.f,0.f};
      f32x4 a2 = (f32x4){0.f,0.f,0.f,0.f}, a3 = (f32x4){0.f,0.f,0.f,0.f};
      if (mw || t > 0) {
        const short* ibr = img[t & 1];
#pragma unroll
        for (int m = 0; m < 8; m++) {
          const int chb = fq + m * 16;
          short8 bv0 = *(const short8*)&ibr[ib + fr * 1024 + (((chb + 0) ^ sw) << 3)];
          short8 bv1 = *(const short8*)&ibr[ib + fr * 1024 + (((chb + 4) ^ sw) << 3)];
          short8 bv2 = *(const short8*)&ibr[ib + fr * 1024 + (((chb + 8) ^ sw) << 3)];
          short8 bv3 = *(const short8*)&ibr[ib + fr * 1024 + (((chb + 12) ^ sw) << 3)];
          a0 = __builtin_amdgcn_mfma_f32_16x16x32_bf16(wreg[4 * m + 0], bv0, a0, 0, 0, 0);
          a1 = __builtin_amdgcn_mfma_f32_16x16x32_bf16(wreg[4 * m + 1], bv1, a1, 0, 0, 0);
          a2 = __builtin_amdgcn_mfma_f32_16x16x32_bf16(wreg[4 * m + 2], bv2, a2, 0, 0, 0);
          a3 = __builtin_amdgcn_mfma_f32_16x16x32_bf16(wreg[4 * m + 3], bv3, a3, 0, 0, 0);
        }
      }
      f32x4 s4 = (a0 + a1) + (a2 + a3);
      if (mw) *(f32x4*)&red[t & 1][(wn * 64 + lane) * 4] = s4;
      __syncthreads();  // #2: Wih1 partials visible

      if (!mw) {
        const f32x4 o4 = *(const f32x4*)&red[t & 1][(wn * 64 + lane) * 4];
        float pre0 = s4[0] + o4[0] + bia[0];
        float pre1 = s4[1] + o4[1] + bia[1];
        float pre2 = s4[2] + o4[2] + bia[2];
        float pre3 = s4[3] + o4[3] + bia[3];

        float iv = 1.f / (1.f + __expf(-pre0));
        float fv = 1.f / (1.f + __expf(-pre1));
        float gv = 2.f / (1.f + __expf(-2.f * pre2)) - 1.f;
        float ov = 1.f / (1.f + __expf(-pre3));
        cell = fv * cell + iv * gv;
        float h = ov * (2.f / (1.f + __expf(-2.f * cell)) - 1.f);

        {
          const short* sb = hs1 + (size_t)t * 32768;
          unsigned int voff = (unsigned int)((b * 1024 + j) * 2);
          unsigned int hv = (unsigned int)f2bf(h);
          asm volatile("global_store_short %0, %1, %2 sc0 sc1"
                       :: "v"(voff), "v"(hv), "s"(sb) : "memory");
        }
        __builtin_nontemporal_store(h, &out[(size_t)b * 524288 + (size_t)t * 1024 + j]);
        if (t == 511) {
          hn[32768 + b * 1024 + j] = h;
          cn[32768 + b * 1024 + j] = cell;
        }
      }
      // no #3: img/red are double-buffered; next step writes the other parity
    }
  }
}

extern "C" void kernel_launch(void* const* d_in, const int* in_sizes, int n_in,
                              void* d_out, int out_size, void* d_ws, size_t ws_size,
                              hipStream_t stream) {
  const float* x    = (const float*)d_in[0];
  const float* Wih0 = (const float*)d_in[1];
  const float* b0   = (const float*)d_in[2];
  const float* Whh0 = (const float*)d_in[3];
  const float* Wih1 = (const float*)d_in[4];
  const float* b1   = (const float*)d_in[5];
  const float* Whh1 = (const float*)d_in[6];

  float* out = (float*)d_out;          // [32][512][1024]
  float* hn  = out + 16777216;         // [2][32][1024]
  float* cn  = hn + 65536;

  char* ws = (char*)d_ws;
  size_t off = 0;
  auto carve = [&](size_t bytes) {
    char* p = ws + off;
    off += (bytes + 255) & ~(size_t)255;
    return p;
  };
  short* xbf   = (short*)carve(16384ull * 1024 * 2);  // reused as hs1 later
  short* wih0p = (short*)carve(4096ull * 1024 * 2);
  short* whh0p = (short*)carve(4096ull * 1024 * 2);
  short* wih1p = (short*)carve(4096ull * 1024 * 2);
  short* whh1p = (short*)carve(4096ull * 1024 * 2);
  float* b0p   = (float*)carve(4096 * 4);
  float* b1p   = (float*)carve(4096 * 4);
  short* gx    = (short*)carve(512ull * 4096 * 32 * 2);  // [t][b][n] layer-0 only
  short* hs0   = (short*)carve(16384ull * 1024 * 2);

  // phase 0: conversions / permutations
  hipLaunchKernelGGL(cvt_x_kernel, dim3(4096), dim3(256), 0, stream, x, xbf);
  hipLaunchKernelGGL(cvt_w_kernel, dim3(1024), dim3(256), 0, stream, Wih0, wih0p);
  hipLaunchKernelGGL(cvt_w_kernel, dim3(1024), dim3(256), 0, stream, Whh0, whh0p);
  hipLaunchKernelGGL(cvt_w_kernel, dim3(1024), dim3(256), 0, stream, Wih1, wih1p);
  hipLaunchKernelGGL(cvt_w_kernel, dim3(1024), dim3(256), 0, stream, Whh1, whh1p);
  hipLaunchKernelGGL(cvt_b_kernel, dim3(16), dim3(256), 0, stream, b0, b0p);
  hipLaunchKernelGGL(cvt_b_kernel, dim3(16), dim3(256), 0, stream, b1, b1p);
  // sentinel-fill hs0 (bf16 0x7F7F) before the recurrence
  hipMemsetAsync(hs0, 0x7F, 16384ull * 1024 * 2, stream);

  // layer-0 input GEMM (layer-1's is computed in-kernel, pipelined)
  hipLaunchKernelGGL(gemm_bt, dim3(32, 128), dim3(256), 0, stream, wih0p, xbf, gx);

  // xbf is dead after gemm -> sentinel-fill and reuse as hs1
  short* hs1 = xbf;
  hipMemsetAsync(hs1, 0x7F, 16384ull * 1024 * 2, stream);

  // fused, pipelined 2-layer recurrence: 64 layer-0 WGs + 128 layer-1 WGs
  hipLaunchKernelGGL(lstm_fused, dim3(192), dim3(512), 0, stream,
                     (const short*)gx, (const short*)whh0p, (const float*)b0p,
                     (const short*)wih1p, (const short*)whh1p, (const float*)b1p,
                     hs0, hs1, out, hn, cn);
}

// Round 4
// 4140.773 us; speedup vs baseline: 1.0400x; 1.0400x over previous
//
#include <hip/hip_runtime.h>
#include <stdint.h>

// ---- types ----
typedef __attribute__((ext_vector_type(8))) short short8;   // 8 bf16 = 4 VGPR (MFMA A/B frag)
typedef __attribute__((ext_vector_type(4))) short short4v;  // 4 bf16 = 8B
typedef __attribute__((ext_vector_type(4))) float f32x4;    // MFMA C/D frag
typedef __attribute__((ext_vector_type(4))) unsigned int u32x4;
typedef __attribute__((ext_vector_type(4))) int i32x4;
typedef __attribute__((ext_vector_type(2))) unsigned long long u64x2;

// ---- bf16 helpers (manual RNE) ----
__device__ inline unsigned short f2bf(float f) {
  unsigned int u = __builtin_bit_cast(unsigned int, f);
  u += 0x7fffu + ((u >> 16) & 1u);
  return (unsigned short)(u >> 16);
}
__device__ inline float bf2f(unsigned short s) {
  return __builtin_bit_cast(float, (unsigned int)s << 16);
}

// sentinel = bf16 0x7F7F (=3.39e38). |h|<1 strictly -> cannot collide with data.
// stale64(v) != 0 iff any 16-bit lane of v equals 0x7F7F.
// Protocol invariant: producers store packed 8B words; an 8B word arrives
// atomically, so "no sentinel anywhere in the 16B chunk" == chunk ready.
__device__ inline unsigned long long stale64(unsigned long long v) {
  unsigned long long x = v ^ 0x7f7f7f7f7f7f7f7full;
  return (x - 0x0001000100010001ull) & ~x & 0x8000800080008000ull;
}

// Problem constants: B=32, T=512, D=H=1024, 4H=4096, M = T*B = 16384
// gx layout: [t][b][n] bf16, n = permuted gate-row (4*j + gate)
// hs layout: [t][b][j]  bf16

// ---- x: [B][T][D] f32  ->  xbf: [m = t*32+b][d] bf16 ----
__global__ __launch_bounds__(256) void cvt_x_kernel(const float* __restrict__ x,
                                                    short* __restrict__ xbf) {
  const int total = (16384 * 1024) / 4;
  for (int i = blockIdx.x * blockDim.x + threadIdx.x; i < total;
       i += gridDim.x * blockDim.x) {
    int d4 = i & 255;
    int m  = i >> 8;
    int t = m >> 5, b = m & 31;
    float4 v = *(const float4*)(x + ((size_t)b * 512 + t) * 1024 + (size_t)d4 * 4);
    short4v o;
    o.x = (short)f2bf(v.x); o.y = (short)f2bf(v.y);
    o.z = (short)f2bf(v.z); o.w = (short)f2bf(v.w);
    *(short4v*)(xbf + (size_t)m * 1024 + d4 * 4) = o;
  }
}

// ---- W: [4096][1024] f32 -> Wp: gate-interleaved rows, bf16. ----
__global__ __launch_bounds__(256) void cvt_w_kernel(const float* __restrict__ W,
                                                    short* __restrict__ Wp) {
  const int total = (4096 * 1024) / 4;
  for (int i = blockIdx.x * blockDim.x + threadIdx.x; i < total;
       i += gridDim.x * blockDim.x) {
    int k4 = i & 255;
    int n  = i >> 8;
    int g = n & 3, j = n >> 2;
    float4 v = *(const float4*)(W + ((size_t)g * 1024 + j) * 1024 + (size_t)k4 * 4);
    short4v o;
    o.x = (short)f2bf(v.x); o.y = (short)f2bf(v.y);
    o.z = (short)f2bf(v.z); o.w = (short)f2bf(v.w);
    *(short4v*)(Wp + (size_t)n * 1024 + k4 * 4) = o;
  }
}

// ---- bias permute (stays f32) ----
__global__ __launch_bounds__(256) void cvt_b_kernel(const float* __restrict__ b,
                                                    float* __restrict__ bp) {
  int n = blockIdx.x * blockDim.x + threadIdx.x;
  if (n < 4096) bp[n] = b[(n & 3) * 1024 + (n >> 2)];
}

// ---- bf16 MFMA GEMM:  C[t][b][n] = sum_k A[n][k] * Bm[m=t*32+b][k] ----
__global__ __launch_bounds__(256) void gemm_bt(const short* __restrict__ A,
                                               const short* __restrict__ Bm,
                                               short* __restrict__ C) {
  const int n0 = blockIdx.x * 128;
  const int m0 = blockIdx.y * 128;
  const int tid = threadIdx.x;
  const int lane = tid & 63, wid = tid >> 6;
  const int wr = wid >> 1, wc = wid & 1;
  const int fr = lane & 15, fq = lane >> 4;

  __shared__ __align__(16) short As[128 * 32];
  __shared__ __align__(16) short Bs[128 * 32];

  f32x4 acc[4][4];
#pragma unroll
  for (int i = 0; i < 4; i++)
#pragma unroll
    for (int j = 0; j < 4; j++) acc[i][j] = (f32x4){0.f, 0.f, 0.f, 0.f};

  for (int kt = 0; kt < 1024; kt += 32) {
#pragma unroll
    for (int s = 0; s < 2; s++) {
      int c = tid + s * 256;
      int row = c >> 2;
      int off = (c & 3) * 8;
      *(u32x4*)&As[row * 32 + off] =
          *(const u32x4*)(A + (size_t)(n0 + row) * 1024 + kt + off);
      *(u32x4*)&Bs[row * 32 + off] =
          *(const u32x4*)(Bm + (size_t)(m0 + row) * 1024 + kt + off);
    }
    __syncthreads();
    short8 af[4], bf[4];
#pragma unroll
    for (int i = 0; i < 4; i++)
      af[i] = *(const short8*)&As[(wr * 64 + i * 16 + fr) * 32 + fq * 8];
#pragma unroll
    for (int j = 0; j < 4; j++)
      bf[j] = *(const short8*)&Bs[(wc * 64 + j * 16 + fr) * 32 + fq * 8];
#pragma unroll
    for (int i = 0; i < 4; i++)
#pragma unroll
      for (int j = 0; j < 4; j++)
        acc[i][j] = __builtin_amdgcn_mfma_f32_16x16x32_bf16(af[i], bf[j], acc[i][j], 0, 0, 0);
    __syncthreads();
  }

#pragma unroll
  for (int i = 0; i < 4; i++) {
#pragma unroll
    for (int j = 0; j < 4; j++) {
      int nq = n0 + wr * 64 + i * 16 + fq * 4;
      int m = m0 + wc * 64 + j * 16 + fr;
      int t = m >> 5, b = m & 31;
      unsigned long long pk = 0;
#pragma unroll
      for (int r = 0; r < 4; r++)
        pk |= (unsigned long long)f2bf(acc[i][j][r]) << (16 * r);
      *(unsigned long long*)&C[(size_t)t * 131072 + (size_t)b * 4096 + nq] = pk;
    }
  }
}

// Full-pull sentinel spin (PROVEN R1 protocol) + s_sleep backoff on failure.
// 8 chunks per thread; writes into ibw (double-buffered image).
#define PULL8_SPIN(HBP)                                                       \
  do {                                                                        \
    i32x4 r0, r1, r2, r3, r4, r5, r6, r7;                                     \
    while (true) {                                                            \
      asm volatile(                                                           \
          "global_load_dwordx4 %0, %8, %16 sc0 sc1\n\t"                       \
          "global_load_dwordx4 %1, %9, %16 sc0 sc1\n\t"                       \
          "global_load_dwordx4 %2, %10, %16 sc0 sc1\n\t"                      \
          "global_load_dwordx4 %3, %11, %16 sc0 sc1\n\t"                      \
          "global_load_dwordx4 %4, %12, %16 sc0 sc1\n\t"                      \
          "global_load_dwordx4 %5, %13, %16 sc0 sc1\n\t"                      \
          "global_load_dwordx4 %6, %14, %16 sc0 sc1\n\t"                      \
          "global_load_dwordx4 %7, %15, %16 sc0 sc1\n\t"                      \
          "s_waitcnt vmcnt(0)"                                                \
          : "=&v"(r0), "=&v"(r1), "=&v"(r2), "=&v"(r3), "=&v"(r4),            \
            "=&v"(r5), "=&v"(r6), "=&v"(r7)                                   \
          : "v"(soff[0]), "v"(soff[1]), "v"(soff[2]), "v"(soff[3]),           \
            "v"(soff[4]), "v"(soff[5]), "v"(soff[6]), "v"(soff[7]),           \
            "s"(HBP)                                                          \
          : "memory");                                                        \
      u64x2 q0 = __builtin_bit_cast(u64x2, r0), q1 = __builtin_bit_cast(u64x2, r1); \
      u64x2 q2 = __builtin_bit_cast(u64x2, r2), q3 = __builtin_bit_cast(u64x2, r3); \
      u64x2 q4 = __builtin_bit_cast(u64x2, r4), q5 = __builtin_bit_cast(u64x2, r5); \
      u64x2 q6 = __builtin_bit_cast(u64x2, r6), q7 = __builtin_bit_cast(u64x2, r7); \
      unsigned long long bad =                                                \
          stale64(q0.x) | stale64(q0.y) | stale64(q1.x) | stale64(q1.y) |     \
          stale64(q2.x) | stale64(q2.y) | stale64(q3.x) | stale64(q3.y) |     \
          stale64(q4.x) | stale64(q4.y) | stale64(q5.x) | stale64(q5.y) |     \
          stale64(q6.x) | stale64(q6.y) | stale64(q7.x) | stale64(q7.y);      \
      if (!bad) break;                                                        \
      __builtin_amdgcn_s_sleep(2);                                            \
    }                                                                         \
    *(i32x4*)&ibw[widx[0]] = r0;                                              \
    *(i32x4*)&ibw[widx[1]] = r1;                                              \
    *(i32x4*)&ibw[widx[2]] = r2;                                              \
    *(i32x4*)&ibw[widx[3]] = r3;                                              \
    *(i32x4*)&ibw[widx[4]] = r4;                                              \
    *(i32x4*)&ibw[widx[5]] = r5;                                              \
    *(i32x4*)&ibw[widx[6]] = r6;                                              \
    *(i32x4*)&ibw[widx[7]] = r7;                                              \
  } while (0)

// ---- fused 2-layer pipelined LSTM ----
// grid = 192 WGs x 512 threads, all resident (1 WG/CU), no inter-group cycles.
//   WGs   0..63 : layer-0 recurrence. WG owns 128 gate-rows x 16 batches.
//   WGs 64..191 : layer-1. WG owns 64 gate-rows x 16 batches; waves 0-3 hold
//                 Whh1 (consume h1[t-1] image), waves 4-7 hold Wih1 (consume
//                 h0[t] image); partial gate sums meet in an LDS red buffer.
// Handoff: PROVEN R1 sentinel-in-data protocol (one hop: data write IS the
// signal; producer 8B packed stores = atomic arrival unit = verify unit).
// vs R1: LDS double-buffered img/red (one barrier dropped per step in each
// layer -- rendezvous ordering proof in session notes), s_sleep spin backoff,
// non-temporal gx/out streams to keep L3 clean for the handoff lines.
__global__ __launch_bounds__(512, 1) void lstm_fused(
    const short* __restrict__ gx0, const short* __restrict__ whh0,
    const float* __restrict__ b0p, const short* __restrict__ wih1,
    const short* __restrict__ whh1, const float* __restrict__ b1p,
    short* __restrict__ hs0, short* __restrict__ hs1,
    float* __restrict__ out, float* __restrict__ hn, float* __restrict__ cn) {
  const int tid = threadIdx.x;
  const int lane = tid & 63, w = tid >> 6;
  const int fr = lane & 15, fq = lane >> 4;

  // double-buffered h images: L0 uses first 16K shorts of each buffer;
  // L1 uses both 16K halves (mw split). 128KB + 8KB red.
  __shared__ __align__(16) short img[2][32768];
  __shared__ __align__(16) float red[2][1024];

  if (blockIdx.x < 64) {
    // ================= layer 0: 128 gate-rows x 16 batches =================
    const int rg = (int)blockIdx.x >> 1, bg = (int)blockIdx.x & 1;
    const int n_base = rg * 128 + w * 16;
    const int b = bg * 16 + fr;
    const int jb = rg * 32 + w * 4;   // wave's output j-quad base
    const int j = jb + fq;
    const int sw = fr & 7;

    const short* arow = whh0 + (size_t)(n_base + fr) * 1024 + fq * 8;
    short8 wreg[32];
#pragma unroll
    for (int kk = 0; kk < 32; kk++) wreg[kk] = *(const short8*)(arow + kk * 32);

    float bia[4];
#pragma unroll
    for (int r = 0; r < 4; r++) bia[r] = b0p[n_base + fq * 4 + r];

    // stage: 2048 16B chunks of the 32KB half-image over 512 threads (4 each)
    unsigned int soff[4];
    int widx[4];
#pragma unroll
    for (int i = 0; i < 4; i++) {
      int ch = tid + i * 512;
      soff[i] = (unsigned int)ch * 16;
      int bb = ch >> 7, cc = ch & 127;
      widx[i] = bb * 1024 + ((cc ^ (bb & 7)) << 3);
    }

    float cell = 0.f;
    for (int t = 0; t < 512; ++t) {
      unsigned long long gq = __builtin_nontemporal_load(
          (const unsigned long long*)(gx0 + (size_t)t * 131072 +
                                      (size_t)b * 4096 + n_base + fq * 4));

      if (t > 0) {
        const short* hbp = hs0 + (size_t)(t - 1) * 32768 + bg * 16384;
        short* ibw = img[t & 1];
        i32x4 r0, r1, r2, r3;
        while (true) {
          asm volatile(
              "global_load_dwordx4 %0, %4, %8 sc0 sc1\n\t"
              "global_load_dwordx4 %1, %5, %8 sc0 sc1\n\t"
              "global_load_dwordx4 %2, %6, %8 sc0 sc1\n\t"
              "global_load_dwordx4 %3, %7, %8 sc0 sc1\n\t"
              "s_waitcnt vmcnt(0)"
              : "=&v"(r0), "=&v"(r1), "=&v"(r2), "=&v"(r3)
              : "v"(soff[0]), "v"(soff[1]), "v"(soff[2]), "v"(soff[3]),
                "s"(hbp)
              : "memory");
          u64x2 q0 = __builtin_bit_cast(u64x2, r0);
          u64x2 q1 = __builtin_bit_cast(u64x2, r1);
          u64x2 q2 = __builtin_bit_cast(u64x2, r2);
          u64x2 q3 = __builtin_bit_cast(u64x2, r3);
          unsigned long long bad =
              stale64(q0.x) | stale64(q0.y) | stale64(q1.x) | stale64(q1.y) |
              stale64(q2.x) | stale64(q2.y) | stale64(q3.x) | stale64(q3.y);
          if (!bad) break;
          __builtin_amdgcn_s_sleep(2);
        }
        *(i32x4*)&ibw[widx[0]] = r0;
        *(i32x4*)&ibw[widx[1]] = r1;
        *(i32x4*)&ibw[widx[2]] = r2;
        *(i32x4*)&ibw[widx[3]] = r3;
      }
      __syncthreads();  // image staged (only barrier: dbuf covers the tail)

      f32x4 a0 = (f32x4){0.f,0.f,0.f,0.f}, a1 = (f32x4){0.f,0.f,0.f,0.f};
      f32x4 a2 = (f32x4){0.f,0.f,0.f,0.f}, a3 = (f32x4){0.f,0.f,0.f,0.f};
      if (t > 0) {
        const short* ibr = img[t & 1];
#pragma unroll
        for (int m = 0; m < 8; m++) {
          const int chb = fq + m * 16;
          short8 bv0 = *(const short8*)&ibr[fr * 1024 + (((chb + 0) ^ sw) << 3)];
          short8 bv1 = *(const short8*)&ibr[fr * 1024 + (((chb + 4) ^ sw) << 3)];
          short8 bv2 = *(const short8*)&ibr[fr * 1024 + (((chb + 8) ^ sw) << 3)];
          short8 bv3 = *(const short8*)&ibr[fr * 1024 + (((chb + 12) ^ sw) << 3)];
          a0 = __builtin_amdgcn_mfma_f32_16x16x32_bf16(wreg[4 * m + 0], bv0, a0, 0, 0, 0);
          a1 = __builtin_amdgcn_mfma_f32_16x16x32_bf16(wreg[4 * m + 1], bv1, a1, 0, 0, 0);
          a2 = __builtin_amdgcn_mfma_f32_16x16x32_bf16(wreg[4 * m + 2], bv2, a2, 0, 0, 0);
          a3 = __builtin_amdgcn_mfma_f32_16x16x32_bf16(wreg[4 * m + 3], bv3, a3, 0, 0, 0);
        }
      }

      float pre0 = (a0[0] + a1[0]) + (a2[0] + a3[0]) + bf2f((unsigned short)(gq & 0xFFFF)) + bia[0];
      float pre1 = (a0[1] + a1[1]) + (a2[1] + a3[1]) + bf2f((unsigned short)((gq >> 16) & 0xFFFF)) + bia[1];
      float pre2 = (a0[2] + a1[2]) + (a2[2] + a3[2]) + bf2f((unsigned short)((gq >> 32) & 0xFFFF)) + bia[2];
      float pre3 = (a0[3] + a1[3]) + (a2[3] + a3[3]) + bf2f((unsigned short)((gq >> 48) & 0xFFFF)) + bia[3];

      float iv = 1.f / (1.f + __expf(-pre0));
      float fv = 1.f / (1.f + __expf(-pre1));
      float gv = 2.f / (1.f + __expf(-2.f * pre2)) - 1.f;
      float ov = 1.f / (1.f + __expf(-pre3));
      cell = fv * cell + iv * gv;
      float h = ov * (2.f / (1.f + __expf(-2.f * cell)) - 1.f);

      // pack 4 gate-columns (lanes fq=0..3, same b) into one 8B coherent store
      unsigned int hu = (unsigned int)f2bf(h);
      unsigned int v1 = __shfl(hu, fr + 16);
      unsigned int v2 = __shfl(hu, fr + 32);
      unsigned int v3 = __shfl(hu, fr + 48);
      if (fq == 0) {
        unsigned long long pk = (unsigned long long)hu |
                                ((unsigned long long)v1 << 16) |
                                ((unsigned long long)v2 << 32) |
                                ((unsigned long long)v3 << 48);
        __hip_atomic_store(
            (unsigned long long*)(hs0 + (size_t)t * 32768 + (size_t)b * 1024 + jb),
            pk, __ATOMIC_RELAXED, __HIP_MEMORY_SCOPE_AGENT);
      }
      if (t == 511) {
        hn[b * 1024 + j] = h;
        cn[b * 1024 + j] = cell;
      }
      // no tail barrier: next step stages into img[(t+1)&1]
    }
  } else {
    // ================= layer 1: 64 gate-rows x 16 batches, dual-matrix =====
    const int idx = (int)blockIdx.x - 64;
    const int rg = idx >> 1, bg = idx & 1;
    const int wn = w & 3, mw = w >> 2;        // mw=0: Whh1/h1, mw=1: Wih1/h0
    const int n_base = rg * 64 + wn * 16;
    const int b = bg * 16 + fr;
    const int jb = rg * 16 + wn * 4;
    const int j = jb + fq;
    const int sw = fr & 7;
    const int ib = mw << 14;                  // LDS image half (shorts)

    const short* wsrc = mw ? wih1 : whh1;
    const short* arow = wsrc + (size_t)(n_base + fr) * 1024 + fq * 8;
    short8 wreg[32];
#pragma unroll
    for (int kk = 0; kk < 32; kk++) wreg[kk] = *(const short8*)(arow + kk * 32);

    float bia[4];
#pragma unroll
    for (int r = 0; r < 4; r++) bia[r] = b1p[n_base + fq * 4 + r];

    // each 256-thread half stages its own 32KB image: 8 chunks/thread
    const int lt = tid & 255;
    unsigned int soff[8];
    int widx[8];
#pragma unroll
    for (int i = 0; i < 8; i++) {
      int ch = lt + i * 256;
      soff[i] = (unsigned int)ch * 16;
      int bb = ch >> 7, cc = ch & 127;
      widx[i] = ib + bb * 1024 + ((cc ^ (bb & 7)) << 3);
    }

    float cell = 0.f;
    for (int t = 0; t < 512; ++t) {
      short* ibw = img[t & 1];
      if (mw) {
        const short* hbp = hs0 + (size_t)t * 32768 + bg * 16384;
        PULL8_SPIN(hbp);
      } else if (t > 0) {
        const short* hbp = hs1 + (size_t)(t - 1) * 32768 + bg * 16384;
        PULL8_SPIN(hbp);
      }
      __syncthreads();  // #1: both images staged

      f32x4 a0 = (f32x4){0.f,0.f,0.f,0.f}, a1 = (f32x4){0.f,0.f,0.f,0.f};
      f32x4 a2 = (f32x4){0.f,0.f,0.f,0.f}, a3 = (f32x4){0.f,0.f,0.f,0.f};
      if (mw || t > 0) {
        const short* ibr = img[t & 1];
#pragma unroll
        for (int m = 0; m < 8; m++) {
          const int chb = fq + m * 16;
          short8 bv0 = *(const short8*)&ibr[ib + fr * 1024 + (((chb + 0) ^ sw) << 3)];
          short8 bv1 = *(const short8*)&ibr[ib + fr * 1024 + (((chb + 4) ^ sw) << 3)];
          short8 bv2 = *(const short8*)&ibr[ib + fr * 1024 + (((chb + 8) ^ sw) << 3)];
          short8 bv3 = *(const short8*)&ibr[ib + fr * 1024 + (((chb + 12) ^ sw) << 3)];
          a0 = __builtin_amdgcn_mfma_f32_16x16x32_bf16(wreg[4 * m + 0], bv0, a0, 0, 0, 0);
          a1 = __builtin_amdgcn_mfma_f32_16x16x32_bf16(wreg[4 * m + 1], bv1, a1, 0, 0, 0);
          a2 = __builtin_amdgcn_mfma_f32_16x16x32_bf16(wreg[4 * m + 2], bv2, a2, 0, 0, 0);
          a3 = __builtin_amdgcn_mfma_f32_16x16x32_bf16(wreg[4 * m + 3], bv3, a3, 0, 0, 0);
        }
      }
      f32x4 s4 = (a0 + a1) + (a2 + a3);
      if (mw) *(f32x4*)&red[t & 1][(wn * 64 + lane) * 4] = s4;
      __syncthreads();  // #2: Wih1 partials visible

      if (!mw) {
        const f32x4 o4 = *(const f32x4*)&red[t & 1][(wn * 64 + lane) * 4];
        float pre0 = s4[0] + o4[0] + bia[0];
        float pre1 = s4[1] + o4[1] + bia[1];
        float pre2 = s4[2] + o4[2] + bia[2];
        float pre3 = s4[3] + o4[3] + bia[3];

        float iv = 1.f / (1.f + __expf(-pre0));
        float fv = 1.f / (1.f + __expf(-pre1));
        float gv = 2.f / (1.f + __expf(-2.f * pre2)) - 1.f;
        float ov = 1.f / (1.f + __expf(-pre3));
        cell = fv * cell + iv * gv;
        float h = ov * (2.f / (1.f + __expf(-2.f * cell)) - 1.f);

        unsigned int hu = (unsigned int)f2bf(h);
        unsigned int v1 = __shfl(hu, fr + 16);
        unsigned int v2 = __shfl(hu, fr + 32);
        unsigned int v3 = __shfl(hu, fr + 48);
        if (fq == 0) {
          unsigned long long pk = (unsigned long long)hu |
                                  ((unsigned long long)v1 << 16) |
                                  ((unsigned long long)v2 << 32) |
                                  ((unsigned long long)v3 << 48);
          __hip_atomic_store(
              (unsigned long long*)(hs1 + (size_t)t * 32768 + (size_t)b * 1024 + jb),
              pk, __ATOMIC_RELAXED, __HIP_MEMORY_SCOPE_AGENT);
        }
        __builtin_nontemporal_store(h, &out[(size_t)b * 524288 + (size_t)t * 1024 + j]);
        if (t == 511) {
          hn[32768 + b * 1024 + j] = h;
          cn[32768 + b * 1024 + j] = cell;
        }
      }
      // no #3: img/red are double-buffered; rendezvous ordering protects them
    }
  }
}

extern "C" void kernel_launch(void* const* d_in, const int* in_sizes, int n_in,
                              void* d_out, int out_size, void* d_ws, size_t ws_size,
                              hipStream_t stream) {
  const float* x    = (const float*)d_in[0];
  const float* Wih0 = (const float*)d_in[1];
  const float* b0   = (const float*)d_in[2];
  const float* Whh0 = (const float*)d_in[3];
  const float* Wih1 = (const float*)d_in[4];
  const float* b1   = (const float*)d_in[5];
  const float* Whh1 = (const float*)d_in[6];

  float* out = (float*)d_out;          // [32][512][1024]
  float* hn  = out + 16777216;         // [2][32][1024]
  float* cn  = hn + 65536;

  char* ws = (char*)d_ws;
  size_t off = 0;
  auto carve = [&](size_t bytes) {
    char* p = ws + off;
    off += (bytes + 255) & ~(size_t)255;
    return p;
  };
  short* xbf   = (short*)carve(16384ull * 1024 * 2);  // reused as hs1 later
  short* wih0p = (short*)carve(4096ull * 1024 * 2);
  short* whh0p = (short*)carve(4096ull * 1024 * 2);
  short* wih1p = (short*)carve(4096ull * 1024 * 2);
  short* whh1p = (short*)carve(4096ull * 1024 * 2);
  float* b0p   = (float*)carve(4096 * 4);
  float* b1p   = (float*)carve(4096 * 4);
  short* gx    = (short*)carve(512ull * 4096 * 32 * 2);  // [t][b][n] layer-0 only
  short* hs0   = (short*)carve(16384ull * 1024 * 2);

  // phase 0: conversions / permutations
  hipLaunchKernelGGL(cvt_x_kernel, dim3(4096), dim3(256), 0, stream, x, xbf);
  hipLaunchKernelGGL(cvt_w_kernel, dim3(1024), dim3(256), 0, stream, Wih0, wih0p);
  hipLaunchKernelGGL(cvt_w_kernel, dim3(1024), dim3(256), 0, stream, Whh0, whh0p);
  hipLaunchKernelGGL(cvt_w_kernel, dim3(1024), dim3(256), 0, stream, Wih1, wih1p);
  hipLaunchKernelGGL(cvt_w_kernel, dim3(1024), dim3(256), 0, stream, Whh1, whh1p);
  hipLaunchKernelGGL(cvt_b_kernel, dim3(16), dim3(256), 0, stream, b0, b0p);
  hipLaunchKernelGGL(cvt_b_kernel, dim3(16), dim3(256), 0, stream, b1, b1p);
  // sentinel-fill hs0 (bf16 0x7F7F) before the recurrence
  hipMemsetAsync(hs0, 0x7F, 16384ull * 1024 * 2, stream);

  // layer-0 input GEMM (layer-1's is computed in-kernel, pipelined)
  hipLaunchKernelGGL(gemm_bt, dim3(32, 128), dim3(256), 0, stream, wih0p, xbf, gx);

  // xbf is dead after gemm -> sentinel-fill and reuse as hs1
  short* hs1 = xbf;
  hipMemsetAsync(hs1, 0x7F, 16384ull * 1024 * 2, stream);

  // fused, pipelined 2-layer recurrence: 64 layer-0 WGs + 128 layer-1 WGs
  hipLaunchKernelGGL(lstm_fused, dim3(192), dim3(512), 0, stream,
                     (const short*)gx, (const short*)whh0p, (const float*)b0p,
                     (const short*)wih1p, (const short*)whh1p, (const float*)b1p,
                     hs0, hs1, out, hn, cn);
}

// Round 6
// 2916.611 us; speedup vs baseline: 1.4764x; 1.4197x over previous
//
#include <hip/hip_runtime.h>
#include <stdint.h>

// ---- types ----
typedef __attribute__((ext_vector_type(8))) short short8;   // 8 bf16 = 4 VGPR (MFMA A/B frag)
typedef __attribute__((ext_vector_type(4))) short short4v;  // 4 bf16 = 8B
typedef __attribute__((ext_vector_type(4))) float f32x4;    // MFMA C/D frag
typedef __attribute__((ext_vector_type(4))) unsigned int u32x4;
typedef __attribute__((ext_vector_type(4))) int i32x4;
typedef __attribute__((ext_vector_type(2))) unsigned long long u64x2;

// ---- bf16 helpers (manual RNE) ----
__device__ inline unsigned short f2bf(float f) {
  unsigned int u = __builtin_bit_cast(unsigned int, f);
  u += 0x7fffu + ((u >> 16) & 1u);
  return (unsigned short)(u >> 16);
}
__device__ inline float bf2f(unsigned short s) {
  return __builtin_bit_cast(float, (unsigned int)s << 16);
}

// sentinel = bf16 0x7F7F (=3.39e38). |h|<1 and |gx|<~10 -> the exact bit
// pattern cannot occur in produced data. stale64(v) != 0 iff any 16-bit lane
// of v equals 0x7F7F. Protocol invariant: producers store packed 8B words
// (atomic arrival unit == verification unit).
__device__ inline unsigned long long stale64(unsigned long long v) {
  unsigned long long x = v ^ 0x7f7f7f7f7f7f7f7full;
  return (x - 0x0001000100010001ull) & ~x & 0x8000800080008000ull;
}

// Problem constants: B=32, T=512, D=H=1024, 4H=4096, M = T*B = 16384
// gx layout: [t][b][n] bf16, n = permuted gate-row (4*j + gate)
// hs layout: [t][b][j]  bf16

// ---- W: [4096][1024] f32 -> Wp: gate-interleaved rows, bf16. ----
__global__ __launch_bounds__(256) void cvt_w_kernel(const float* __restrict__ W,
                                                    short* __restrict__ Wp) {
  const int total = (4096 * 1024) / 4;
  for (int i = blockIdx.x * blockDim.x + threadIdx.x; i < total;
       i += gridDim.x * blockDim.x) {
    int k4 = i & 255;
    int n  = i >> 8;
    int g = n & 3, j = n >> 2;
    float4 v = *(const float4*)(W + ((size_t)g * 1024 + j) * 1024 + (size_t)k4 * 4);
    short4v o;
    o.x = (short)f2bf(v.x); o.y = (short)f2bf(v.y);
    o.z = (short)f2bf(v.z); o.w = (short)f2bf(v.w);
    *(short4v*)(Wp + (size_t)n * 1024 + k4 * 4) = o;
  }
}

// ---- bias permute (stays f32) ----
__global__ __launch_bounds__(256) void cvt_b_kernel(const float* __restrict__ b,
                                                    float* __restrict__ bp) {
  int n = blockIdx.x * blockDim.x + threadIdx.x;
  if (n < 4096) bp[n] = b[(n & 3) * 1024 + (n >> 2)];
}

// Full-pull sentinel spin (PROVEN R1 protocol). 8 chunks per thread; writes
// into the single-buffered image at widx[]. No sleep, no probes: exactly R1.
#define PULL8_SPIN(HBP)                                                       \
  do {                                                                        \
    i32x4 r0, r1, r2, r3, r4, r5, r6, r7;                                     \
    while (true) {                                                            \
      asm volatile(                                                           \
          "global_load_dwordx4 %0, %8, %16 sc0 sc1\n\t"                       \
          "global_load_dwordx4 %1, %9, %16 sc0 sc1\n\t"                       \
          "global_load_dwordx4 %2, %10, %16 sc0 sc1\n\t"                      \
          "global_load_dwordx4 %3, %11, %16 sc0 sc1\n\t"                      \
          "global_load_dwordx4 %4, %12, %16 sc0 sc1\n\t"                      \
          "global_load_dwordx4 %5, %13, %16 sc0 sc1\n\t"                      \
          "global_load_dwordx4 %6, %14, %16 sc0 sc1\n\t"                      \
          "global_load_dwordx4 %7, %15, %16 sc0 sc1\n\t"                      \
          "s_waitcnt vmcnt(0)"                                                \
          : "=&v"(r0), "=&v"(r1), "=&v"(r2), "=&v"(r3), "=&v"(r4),            \
            "=&v"(r5), "=&v"(r6), "=&v"(r7)                                   \
          : "v"(soff[0]), "v"(soff[1]), "v"(soff[2]), "v"(soff[3]),           \
            "v"(soff[4]), "v"(soff[5]), "v"(soff[6]), "v"(soff[7]),           \
            "s"(HBP)                                                          \
          : "memory");                                                        \
      u64x2 q0 = __builtin_bit_cast(u64x2, r0), q1 = __builtin_bit_cast(u64x2, r1); \
      u64x2 q2 = __builtin_bit_cast(u64x2, r2), q3 = __builtin_bit_cast(u64x2, r3); \
      u64x2 q4 = __builtin_bit_cast(u64x2, r4), q5 = __builtin_bit_cast(u64x2, r5); \
      u64x2 q6 = __builtin_bit_cast(u64x2, r6), q7 = __builtin_bit_cast(u64x2, r7); \
      unsigned long long bad =                                                \
          stale64(q0.x) | stale64(q0.y) | stale64(q1.x) | stale64(q1.y) |     \
          stale64(q2.x) | stale64(q2.y) | stale64(q3.x) | stale64(q3.y) |     \
          stale64(q4.x) | stale64(q4.y) | stale64(q5.x) | stale64(q5.y) |     \
          stale64(q6.x) | stale64(q6.y) | stale64(q7.x) | stale64(q7.y);      \
      if (!bad) break;                                                        \
    }                                                                         \
    *(i32x4*)&img[widx[0]] = r0;                                              \
    *(i32x4*)&img[widx[1]] = r1;                                              \
    *(i32x4*)&img[widx[2]] = r2;                                              \
    *(i32x4*)&img[widx[3]] = r3;                                              \
    *(i32x4*)&img[widx[4]] = r4;                                              \
    *(i32x4*)&img[widx[5]] = r5;                                              \
    *(i32x4*)&img[widx[6]] = r6;                                              \
    *(i32x4*)&img[widx[7]] = r7;                                              \
  } while (0)

// ---- fused 3-group pipelined LSTM ----
// grid = 256 WGs x 512 threads, all resident (1 WG/CU), DAG acyclic:
//   WGs   0..63  : G  = gx GEMM (gx[t] = Wih0^T x[t]), tiles t-ascending,
//                  reads x f32 directly (cvt fused into staging), publishes
//                  packed 8B sc0sc1 stores into sentinel-filled gx.
//   WGs  64..127 : L0 = layer-0 recurrence (EXACT R1 code; gq load is now a
//                  sentinel-checked sc0sc1 load, single-shot after warmup).
//   WGs 128..255 : L1 = layer-1 (EXACT R1 code).
// Handoff: PROVEN R1 sentinel-in-data protocol everywhere.
__global__ __launch_bounds__(512, 1) void lstm_fused(
    const float* __restrict__ x, const short* __restrict__ wih0p,
    const short* __restrict__ whh0, const float* __restrict__ b0p,
    const short* __restrict__ wih1, const short* __restrict__ whh1,
    const float* __restrict__ b1p, short* __restrict__ gx0,
    short* __restrict__ hs0, short* __restrict__ hs1,
    float* __restrict__ out, float* __restrict__ hn, float* __restrict__ cn) {
  const int tid = threadIdx.x;
  const int lane = tid & 63, w = tid >> 6;
  const int fr = lane & 15, fq = lane >> 4;

  __shared__ __align__(16) short img[32 * 1024];   // L0/L1 h-image; G: As|Bs
  __shared__ __align__(16) float red[4 * 64 * 4];  // L1 k-partial exchange

  if (blockIdx.x < 64) {
    // ================= G: streaming gx GEMM, t-ascending tiles =============
    short* As = img;          // [128][32] bf16 = 8KB
    short* Bs = img + 4096;   // [128][32] bf16 = 8KB
    const int wr = w >> 1, wc = w & 1;  // 4x2 wave grid: 32n x 64m per wave

    for (int T = (int)blockIdx.x; T < 4096; T += 64) {
      const int mt = T >> 5, nt = T & 31;   // m-major: t ascends with T
      const int n0 = nt * 128, m0 = mt * 128;

      f32x4 acc[2][4];
#pragma unroll
      for (int i = 0; i < 2; i++)
#pragma unroll
        for (int j = 0; j < 4; j++) acc[i][j] = (f32x4){0.f, 0.f, 0.f, 0.f};

      for (int kt = 0; kt < 1024; kt += 32) {
        {
          int row = tid >> 2;
          int off = (tid & 3) * 8;
          *(u32x4*)&As[row * 32 + off] =
              *(const u32x4*)(wih0p + (size_t)(n0 + row) * 1024 + kt + off);
          int m = m0 + row;
          int tt = m >> 5, bb = m & 31;
          const float* xp = x + ((size_t)bb * 512 + tt) * 1024 + kt + off;
          float4 va = *(const float4*)xp;
          float4 vb = *(const float4*)(xp + 4);
          short8 o;
          o[0] = (short)f2bf(va.x); o[1] = (short)f2bf(va.y);
          o[2] = (short)f2bf(va.z); o[3] = (short)f2bf(va.w);
          o[4] = (short)f2bf(vb.x); o[5] = (short)f2bf(vb.y);
          o[6] = (short)f2bf(vb.z); o[7] = (short)f2bf(vb.w);
          *(short8*)&Bs[row * 32 + off] = o;
        }
        __syncthreads();
        short8 af[2], bfr[4];
#pragma unroll
        for (int i = 0; i < 2; i++)
          af[i] = *(const short8*)&As[(wr * 32 + i * 16 + fr) * 32 + fq * 8];
#pragma unroll
        for (int j = 0; j < 4; j++)
          bfr[j] = *(const short8*)&Bs[(wc * 64 + j * 16 + fr) * 32 + fq * 8];
#pragma unroll
        for (int i = 0; i < 2; i++)
#pragma unroll
          for (int j = 0; j < 4; j++)
            acc[i][j] = __builtin_amdgcn_mfma_f32_16x16x32_bf16(af[i], bfr[j], acc[i][j], 0, 0, 0);
        __syncthreads();
      }

#pragma unroll
      for (int i = 0; i < 2; i++) {
#pragma unroll
        for (int j = 0; j < 4; j++) {
          int nq = n0 + wr * 32 + i * 16 + fq * 4;
          int m = m0 + wc * 64 + j * 16 + fr;
          int tt = m >> 5, bb = m & 31;
          unsigned long long pk = 0;
#pragma unroll
          for (int r = 0; r < 4; r++)
            pk |= (unsigned long long)f2bf(acc[i][j][r]) << (16 * r);
          // base must be wave-uniform for saddr; fold lane-divergent tt into
          // the 32-bit voffset (max ~134MB < 4GB).
          unsigned int voff =
              (unsigned int)(((unsigned)tt * 131072u + (unsigned)bb * 4096u +
                              (unsigned)nq) * 2u);
          asm volatile("global_store_dwordx2 %0, %1, %2 sc0 sc1"
                       :: "v"(voff), "v"(pk), "s"(gx0) : "memory");
        }
      }
    }
  } else if (blockIdx.x < 128) {
    // ================= layer 0: 128 gate-rows x 16 batches (EXACT R1) ======
    const int idx0 = (int)blockIdx.x - 64;
    const int bg = idx0 & 1;
    const int n_base = (idx0 >> 1) * 128 + w * 16;
    const int b = bg * 16 + fr;
    const int jb = (idx0 >> 1) * 32 + w * 4;   // wave's output j-quad base
    const int j = jb + fq;
    const int sw = fr & 7;

    const short* arow = whh0 + (size_t)(n_base + fr) * 1024 + fq * 8;
    short8 wreg[32];
#pragma unroll
    for (int kk = 0; kk < 32; kk++) wreg[kk] = *(const short8*)(arow + kk * 32);

    float bia[4];
#pragma unroll
    for (int r = 0; r < 4; r++) bia[r] = b0p[n_base + fq * 4 + r];

    // stage: 2048 16B chunks of the 32KB half-image over 512 threads (4 each)
    unsigned int soff[4];
    int widx[4];
#pragma unroll
    for (int i = 0; i < 4; i++) {
      int ch = tid + i * 512;
      soff[i] = (unsigned int)ch * 16;
      int bb = ch >> 7, cc = ch & 127;
      widx[i] = bb * 1024 + ((cc ^ (bb & 7)) << 3);
    }
    const unsigned int goff = (unsigned int)(((unsigned)b * 4096 + n_base + fq * 4) * 2);

    float cell = 0.f;
    for (int t = 0; t < 512; ++t) {
      // gq: sentinel-checked load (G publishes packed 8B quads; single-shot
      // after G's warmup since G runs ~3x ahead of the recurrence pace)
      unsigned long long gq;
      {
        const short* gb = gx0 + (size_t)t * 131072;
        while (true) {
          asm volatile("global_load_dwordx2 %0, %1, %2 sc0 sc1\n\t"
                       "s_waitcnt vmcnt(0)"
                       : "=v"(gq) : "v"(goff), "s"(gb) : "memory");
          if (!__any((int)(stale64(gq) != 0ull))) break;
          __builtin_amdgcn_s_sleep(1);
        }
      }

      if (t > 0) {
        const short* hbp = hs0 + (size_t)(t - 1) * 32768 + bg * 16384;
        i32x4 r0, r1, r2, r3;
        while (true) {
          asm volatile(
              "global_load_dwordx4 %0, %4, %8 sc0 sc1\n\t"
              "global_load_dwordx4 %1, %5, %8 sc0 sc1\n\t"
              "global_load_dwordx4 %2, %6, %8 sc0 sc1\n\t"
              "global_load_dwordx4 %3, %7, %8 sc0 sc1\n\t"
              "s_waitcnt vmcnt(0)"
              : "=&v"(r0), "=&v"(r1), "=&v"(r2), "=&v"(r3)
              : "v"(soff[0]), "v"(soff[1]), "v"(soff[2]), "v"(soff[3]),
                "s"(hbp)
              : "memory");
          u64x2 q0 = __builtin_bit_cast(u64x2, r0);
          u64x2 q1 = __builtin_bit_cast(u64x2, r1);
          u64x2 q2 = __builtin_bit_cast(u64x2, r2);
          u64x2 q3 = __builtin_bit_cast(u64x2, r3);
          unsigned long long bad =
              stale64(q0.x) | stale64(q0.y) | stale64(q1.x) | stale64(q1.y) |
              stale64(q2.x) | stale64(q2.y) | stale64(q3.x) | stale64(q3.y);
          if (!bad) break;
        }
        *(i32x4*)&img[widx[0]] = r0;
        *(i32x4*)&img[widx[1]] = r1;
        *(i32x4*)&img[widx[2]] = r2;
        *(i32x4*)&img[widx[3]] = r3;
      }
      __syncthreads();  // LDS h-image ready

      f32x4 a0 = (f32x4){0.f,0.f,0.f,0.f}, a1 = (f32x4){0.f,0.f,0.f,0.f};
      f32x4 a2 = (f32x4){0.f,0.f,0.f,0.f}, a3 = (f32x4){0.f,0.f,0.f,0.f};
      if (t > 0) {
#pragma unroll
        for (int m = 0; m < 8; m++) {
          const int chb = fq + m * 16;
          short8 bv0 = *(const short8*)&img[fr * 1024 + (((chb + 0) ^ sw) << 3)];
          short8 bv1 = *(const short8*)&img[fr * 1024 + (((chb + 4) ^ sw) << 3)];
          short8 bv2 = *(const short8*)&img[fr * 1024 + (((chb + 8) ^ sw) << 3)];
          short8 bv3 = *(const short8*)&img[fr * 1024 + (((chb + 12) ^ sw) << 3)];
          a0 = __builtin_amdgcn_mfma_f32_16x16x32_bf16(wreg[4 * m + 0], bv0, a0, 0, 0, 0);
          a1 = __builtin_amdgcn_mfma_f32_16x16x32_bf16(wreg[4 * m + 1], bv1, a1, 0, 0, 0);
          a2 = __builtin_amdgcn_mfma_f32_16x16x32_bf16(wreg[4 * m + 2], bv2, a2, 0, 0, 0);
          a3 = __builtin_amdgcn_mfma_f32_16x16x32_bf16(wreg[4 * m + 3], bv3, a3, 0, 0, 0);
        }
      }

      float pre0 = (a0[0] + a1[0]) + (a2[0] + a3[0]) + bf2f((unsigned short)(gq & 0xFFFF)) + bia[0];
      float pre1 = (a0[1] + a1[1]) + (a2[1] + a3[1]) + bf2f((unsigned short)((gq >> 16) & 0xFFFF)) + bia[1];
      float pre2 = (a0[2] + a1[2]) + (a2[2] + a3[2]) + bf2f((unsigned short)((gq >> 32) & 0xFFFF)) + bia[2];
      float pre3 = (a0[3] + a1[3]) + (a2[3] + a3[3]) + bf2f((unsigned short)((gq >> 48) & 0xFFFF)) + bia[3];

      float iv = 1.f / (1.f + __expf(-pre0));
      float fv = 1.f / (1.f + __expf(-pre1));
      float gv = 2.f / (1.f + __expf(-2.f * pre2)) - 1.f;
      float ov = 1.f / (1.f + __expf(-pre3));
      cell = fv * cell + iv * gv;
      float h = ov * (2.f / (1.f + __expf(-2.f * cell)) - 1.f);

      // pack 4 gate-columns (lanes fq=0..3, same b) into one 8B coherent store
      unsigned int hu = (unsigned int)f2bf(h);
      unsigned int v1 = __shfl(hu, fr + 16);
      unsigned int v2 = __shfl(hu, fr + 32);
      unsigned int v3 = __shfl(hu, fr + 48);
      if (fq == 0) {
        unsigned long long pk = (unsigned long long)hu |
                                ((unsigned long long)v1 << 16) |
                                ((unsigned long long)v2 << 32) |
                                ((unsigned long long)v3 << 48);
        __hip_atomic_store(
            (unsigned long long*)(hs0 + (size_t)t * 32768 + (size_t)b * 1024 + jb),
            pk, __ATOMIC_RELAXED, __HIP_MEMORY_SCOPE_AGENT);
      }
      if (t == 511) {
        hn[b * 1024 + j] = h;
        cn[b * 1024 + j] = cell;
        break;
      }
      __syncthreads();  // protect LDS image until all waves' k-loop reads done
    }
  } else {
    // ================= layer 1: 64 gate-rows x 16 batches (EXACT R1) =======
    const int idx = (int)blockIdx.x - 128;
    const int rg = idx >> 1, bg = idx & 1;
    const int wn = w & 3, mw = w >> 2;        // mw=0: Whh1/h1, mw=1: Wih1/h0
    const int n_base = rg * 64 + wn * 16;
    const int b = bg * 16 + fr;
    const int jb = rg * 16 + wn * 4;
    const int j = jb + fq;
    const int sw = fr & 7;
    const int ib = mw << 14;                  // LDS image half (shorts)

    const short* wsrc = mw ? wih1 : whh1;
    const short* arow = wsrc + (size_t)(n_base + fr) * 1024 + fq * 8;
    short8 wreg[32];
#pragma unroll
    for (int kk = 0; kk < 32; kk++) wreg[kk] = *(const short8*)(arow + kk * 32);

    float bia[4];
#pragma unroll
    for (int r = 0; r < 4; r++) bia[r] = b1p[n_base + fq * 4 + r];

    // each 256-thread half stages its own 32KB image: 8 chunks/thread
    const int lt = tid & 255;
    unsigned int soff[8];
    int widx[8];
#pragma unroll
    for (int i = 0; i < 8; i++) {
      int ch = lt + i * 256;
      soff[i] = (unsigned int)ch * 16;
      int bb = ch >> 7, cc = ch & 127;
      widx[i] = ib + bb * 1024 + ((cc ^ (bb & 7)) << 3);
    }

    float cell = 0.f;
    for (int t = 0; t < 512; ++t) {
      if (mw) {
        const short* hbp = hs0 + (size_t)t * 32768 + bg * 16384;
        PULL8_SPIN(hbp);
      } else if (t > 0) {
        const short* hbp = hs1 + (size_t)(t - 1) * 32768 + bg * 16384;
        PULL8_SPIN(hbp);
      }
      __syncthreads();  // #1: both images staged

      f32x4 a0 = (f32x4){0.f,0.f,0.f,0.f}, a1 = (f32x4){0.f,0.f,0.f,0.f};
      f32x4 a2 = (f32x4){0.f,0.f,0.f,0.f}, a3 = (f32x4){0.f,0.f,0.f,0.f};
      if (mw || t > 0) {
#pragma unroll
        for (int m = 0; m < 8; m++) {
          const int chb = fq + m * 16;
          short8 bv0 = *(const short8*)&img[ib + fr * 1024 + (((chb + 0) ^ sw) << 3)];
          short8 bv1 = *(const short8*)&img[ib + fr * 1024 + (((chb + 4) ^ sw) << 3)];
          short8 bv2 = *(const short8*)&img[ib + fr * 1024 + (((chb + 8) ^ sw) << 3)];
          short8 bv3 = *(const short8*)&img[ib + fr * 1024 + (((chb + 12) ^ sw) << 3)];
          a0 = __builtin_amdgcn_mfma_f32_16x16x32_bf16(wreg[4 * m + 0], bv0, a0, 0, 0, 0);
          a1 = __builtin_amdgcn_mfma_f32_16x16x32_bf16(wreg[4 * m + 1], bv1, a1, 0, 0, 0);
          a2 = __builtin_amdgcn_mfma_f32_16x16x32_bf16(wreg[4 * m + 2], bv2, a2, 0, 0, 0);
          a3 = __builtin_amdgcn_mfma_f32_16x16x32_bf16(wreg[4 * m + 3], bv3, a3, 0, 0, 0);
        }
      }
      f32x4 s4 = (a0 + a1) + (a2 + a3);
      if (mw) *(f32x4*)&red[(wn * 64 + lane) * 4] = s4;
      __syncthreads();  // #2: Wih1 partials visible

      if (!mw) {
        const f32x4 o4 = *(const f32x4*)&red[(wn * 64 + lane) * 4];
        float pre0 = s4[0] + o4[0] + bia[0];
        float pre1 = s4[1] + o4[1] + bia[1];
        float pre2 = s4[2] + o4[2] + bia[2];
        float pre3 = s4[3] + o4[3] + bia[3];

        float iv = 1.f / (1.f + __expf(-pre0));
        float fv = 1.f / (1.f + __expf(-pre1));
        float gv = 2.f / (1.f + __expf(-2.f * pre2)) - 1.f;
        float ov = 1.f / (1.f + __expf(-pre3));
        cell = fv * cell + iv * gv;
        float h = ov * (2.f / (1.f + __expf(-2.f * cell)) - 1.f);

        unsigned int hu = (unsigned int)f2bf(h);
        unsigned int v1 = __shfl(hu, fr + 16);
        unsigned int v2 = __shfl(hu, fr + 32);
        unsigned int v3 = __shfl(hu, fr + 48);
        if (fq == 0) {
          unsigned long long pk = (unsigned long long)hu |
                                  ((unsigned long long)v1 << 16) |
                                  ((unsigned long long)v2 << 32) |
                                  ((unsigned long long)v3 << 48);
          __hip_atomic_store(
              (unsigned long long*)(hs1 + (size_t)t * 32768 + (size_t)b * 1024 + jb),
              pk, __ATOMIC_RELAXED, __HIP_MEMORY_SCOPE_AGENT);
        }
        out[(size_t)b * 524288 + (size_t)t * 1024 + j] = h;
        if (t == 511) {
          hn[32768 + b * 1024 + j] = h;
          cn[32768 + b * 1024 + j] = cell;
        }
      }
      if (t == 511) break;
      __syncthreads();  // #3: protect LDS image/red until all reads done
    }
  }
}

extern "C" void kernel_launch(void* const* d_in, const int* in_sizes, int n_in,
                              void* d_out, int out_size, void* d_ws, size_t ws_size,
                              hipStream_t stream) {
  const float* x    = (const float*)d_in[0];
  const float* Wih0 = (const float*)d_in[1];
  const float* b0   = (const float*)d_in[2];
  const float* Whh0 = (const float*)d_in[3];
  const float* Wih1 = (const float*)d_in[4];
  const float* b1   = (const float*)d_in[5];
  const float* Whh1 = (const float*)d_in[6];

  float* out = (float*)d_out;          // [32][512][1024]
  float* hn  = out + 16777216;         // [2][32][1024]
  float* cn  = hn + 65536;

  char* ws = (char*)d_ws;
  size_t off = 0;
  auto carve = [&](size_t bytes) {
    char* p = ws + off;
    off += (bytes + 255) & ~(size_t)255;
    return p;
  };
  short* wih0p = (short*)carve(4096ull * 1024 * 2);
  short* whh0p = (short*)carve(4096ull * 1024 * 2);
  short* wih1p = (short*)carve(4096ull * 1024 * 2);
  short* whh1p = (short*)carve(4096ull * 1024 * 2);
  float* b0p   = (float*)carve(4096 * 4);
  float* b1p   = (float*)carve(4096 * 4);
  short* gx    = (short*)carve(512ull * 4096 * 32 * 2);  // [t][b][n]
  short* hs0   = (short*)carve(16384ull * 1024 * 2);
  short* hs1   = (short*)carve(16384ull * 1024 * 2);

  // phase 0: weight/bias conversions + sentinel fills (gx now sentinel too,
  // since the gx GEMM runs inside the fused kernel)
  hipLaunchKernelGGL(cvt_w_kernel, dim3(1024), dim3(256), 0, stream, Wih0, wih0p);
  hipLaunchKernelGGL(cvt_w_kernel, dim3(1024), dim3(256), 0, stream, Whh0, whh0p);
  hipLaunchKernelGGL(cvt_w_kernel, dim3(1024), dim3(256), 0, stream, Wih1, wih1p);
  hipLaunchKernelGGL(cvt_w_kernel, dim3(1024), dim3(256), 0, stream, Whh1, whh1p);
  hipLaunchKernelGGL(cvt_b_kernel, dim3(16), dim3(256), 0, stream, b0, b0p);
  hipLaunchKernelGGL(cvt_b_kernel, dim3(16), dim3(256), 0, stream, b1, b1p);
  (void)hipMemsetAsync(gx,  0x7F, 512ull * 4096 * 32 * 2, stream);
  (void)hipMemsetAsync(hs0, 0x7F, 16384ull * 1024 * 2, stream);
  (void)hipMemsetAsync(hs1, 0x7F, 16384ull * 1024 * 2, stream);

  // fused: 64 gx-GEMM WGs + 64 layer-0 WGs + 128 layer-1 WGs (full machine)
  hipLaunchKernelGGL(lstm_fused, dim3(256), dim3(512), 0, stream,
                     x, (const short*)wih0p, (const short*)whh0p, (const float*)b0p,
                     (const short*)wih1p, (const short*)whh1p, (const float*)b1p,
                     gx, hs0, hs1, out, hn, cn);
}

// Round 8
// 2095.697 us; speedup vs baseline: 2.0548x; 1.3917x over previous
//
#include <hip/hip_runtime.h>
#include <stdint.h>

// ---- types ----
typedef __attribute__((ext_vector_type(8))) short short8;   // 8 bf16 = 4 VGPR (MFMA A/B frag)
typedef __attribute__((ext_vector_type(4))) short short4v;  // 4 bf16 = 8B
typedef __attribute__((ext_vector_type(4))) float f32x4;    // MFMA C/D frag
typedef __attribute__((ext_vector_type(4))) unsigned int u32x4;
typedef __attribute__((ext_vector_type(4))) int i32x4;
typedef __attribute__((ext_vector_type(2))) unsigned long long u64x2;

// ---- bf16 helpers (manual RNE) ----
__device__ inline unsigned short f2bf(float f) {
  unsigned int u = __builtin_bit_cast(unsigned int, f);
  u += 0x7fffu + ((u >> 16) & 1u);
  return (unsigned short)(u >> 16);
}
__device__ inline float bf2f(unsigned short s) {
  return __builtin_bit_cast(float, (unsigned int)s << 16);
}

// sentinel = bf16 0x7F7F (=3.39e38). |h|<1 strictly -> cannot collide with data.
// stale64(v) != 0 iff any 16-bit lane of v equals 0x7F7F.
// Protocol invariant: producers store packed 8B words; an 8B word arrives
// atomically, so "no sentinel in the pulled chunk" == chunk ready.
__device__ inline unsigned long long stale64(unsigned long long v) {
  unsigned long long x = v ^ 0x7f7f7f7f7f7f7f7full;
  return (x - 0x0001000100010001ull) & ~x & 0x8000800080008000ull;
}

// Problem constants: B=32, T=512, D=H=1024, 4H=4096, M = T*B = 16384
// gx layout: [t][b][n] bf16, n = permuted gate-row (4*j + gate)
// hs layout: [t][b][j]  bf16

// ---- W: [4096][1024] f32 -> Wp: gate-interleaved rows, bf16. ----
__global__ __launch_bounds__(256) void cvt_w_kernel(const float* __restrict__ W,
                                                    short* __restrict__ Wp) {
  const int total = (4096 * 1024) / 4;
  for (int i = blockIdx.x * blockDim.x + threadIdx.x; i < total;
       i += gridDim.x * blockDim.x) {
    int k4 = i & 255;
    int n  = i >> 8;
    int g = n & 3, j = n >> 2;
    float4 v = *(const float4*)(W + ((size_t)g * 1024 + j) * 1024 + (size_t)k4 * 4);
    short4v o;
    o.x = (short)f2bf(v.x); o.y = (short)f2bf(v.y);
    o.z = (short)f2bf(v.z); o.w = (short)f2bf(v.w);
    *(short4v*)(Wp + (size_t)n * 1024 + k4 * 4) = o;
  }
}

// ---- bias permute (stays f32) ----
__global__ __launch_bounds__(256) void cvt_b_kernel(const float* __restrict__ b,
                                                    float* __restrict__ bp) {
  int n = blockIdx.x * blockDim.x + threadIdx.x;
  if (n < 4096) bp[n] = b[(n & 3) * 1024 + (n >> 2)];
}

// ---- bf16 MFMA GEMM with fused x-conversion:
//   C[t][b][n] = sum_k A[n][k] * bf16(x[b][t][k]),  m = t*32+b
// B-staging reads x in f32 and converts in-register (proven in R6's G group);
// this removes the separate cvt_x pass and the xbf round-trip. ----
__global__ __launch_bounds__(256) void gemm_btx(const short* __restrict__ A,
                                                const float* __restrict__ x,
                                                short* __restrict__ C) {
  const int n0 = blockIdx.x * 128;
  const int m0 = blockIdx.y * 128;
  const int tid = threadIdx.x;
  const int lane = tid & 63, wid = tid >> 6;
  const int wr = wid >> 1, wc = wid & 1;
  const int fr = lane & 15, fq = lane >> 4;

  __shared__ __align__(16) short As[128 * 32];
  __shared__ __align__(16) short Bs[128 * 32];

  f32x4 acc[4][4];
#pragma unroll
  for (int i = 0; i < 4; i++)
#pragma unroll
    for (int j = 0; j < 4; j++) acc[i][j] = (f32x4){0.f, 0.f, 0.f, 0.f};

  for (int kt = 0; kt < 1024; kt += 32) {
#pragma unroll
    for (int s = 0; s < 2; s++) {
      int c = tid + s * 256;
      int row = c >> 2;
      int off = (c & 3) * 8;
      *(u32x4*)&As[row * 32 + off] =
          *(const u32x4*)(A + (size_t)(n0 + row) * 1024 + kt + off);
      int m = m0 + row;
      int tt = m >> 5, bb = m & 31;
      const float* xp = x + ((size_t)bb * 512 + tt) * 1024 + kt + off;
      float4 va = *(const float4*)xp;
      float4 vb = *(const float4*)(xp + 4);
      short8 o;
      o[0] = (short)f2bf(va.x); o[1] = (short)f2bf(va.y);
      o[2] = (short)f2bf(va.z); o[3] = (short)f2bf(va.w);
      o[4] = (short)f2bf(vb.x); o[5] = (short)f2bf(vb.y);
      o[6] = (short)f2bf(vb.z); o[7] = (short)f2bf(vb.w);
      *(short8*)&Bs[row * 32 + off] = o;
    }
    __syncthreads();
    short8 af[4], bf[4];
#pragma unroll
    for (int i = 0; i < 4; i++)
      af[i] = *(const short8*)&As[(wr * 64 + i * 16 + fr) * 32 + fq * 8];
#pragma unroll
    for (int j = 0; j < 4; j++)
      bf[j] = *(const short8*)&Bs[(wc * 64 + j * 16 + fr) * 32 + fq * 8];
#pragma unroll
    for (int i = 0; i < 4; i++)
#pragma unroll
      for (int j = 0; j < 4; j++)
        acc[i][j] = __builtin_amdgcn_mfma_f32_16x16x32_bf16(af[i], bf[j], acc[i][j], 0, 0, 0);
    __syncthreads();
  }

#pragma unroll
  for (int i = 0; i < 4; i++) {
#pragma unroll
    for (int j = 0; j < 4; j++) {
      int nq = n0 + wr * 64 + i * 16 + fq * 4;
      int m = m0 + wc * 64 + j * 16 + fr;
      int t = m >> 5, b = m & 31;
      unsigned long long pk = 0;
#pragma unroll
      for (int r = 0; r < 4; r++)
        pk |= (unsigned long long)f2bf(acc[i][j][r]) << (16 * r);
      *(unsigned long long*)&C[(size_t)t * 131072 + (size_t)b * 4096 + nq] = pk;
    }
  }
}

// 8-chunk sentinel poll into the LDS image (uses locals soff[8], widx[8], img)
// EXACT R1 protocol.
#define POLL8(HBP)                                                            \
  do {                                                                        \
    i32x4 r0, r1, r2, r3, r4, r5, r6, r7;                                     \
    while (true) {                                                            \
      asm volatile(                                                           \
          "global_load_dwordx4 %0, %8, %16 sc0 sc1\n\t"                       \
          "global_load_dwordx4 %1, %9, %16 sc0 sc1\n\t"                       \
          "global_load_dwordx4 %2, %10, %16 sc0 sc1\n\t"                      \
          "global_load_dwordx4 %3, %11, %16 sc0 sc1\n\t"                      \
          "global_load_dwordx4 %4, %12, %16 sc0 sc1\n\t"                      \
          "global_load_dwordx4 %5, %13, %16 sc0 sc1\n\t"                      \
          "global_load_dwordx4 %6, %14, %16 sc0 sc1\n\t"                      \
          "global_load_dwordx4 %7, %15, %16 sc0 sc1\n\t"                      \
          "s_waitcnt vmcnt(0)"                                                \
          : "=&v"(r0), "=&v"(r1), "=&v"(r2), "=&v"(r3), "=&v"(r4),            \
            "=&v"(r5), "=&v"(r6), "=&v"(r7)                                   \
          : "v"(soff[0]), "v"(soff[1]), "v"(soff[2]), "v"(soff[3]),           \
            "v"(soff[4]), "v"(soff[5]), "v"(soff[6]), "v"(soff[7]),           \
            "s"(HBP)                                                          \
          : "memory");                                                        \
      u64x2 q0 = __builtin_bit_cast(u64x2, r0), q1 = __builtin_bit_cast(u64x2, r1); \
      u64x2 q2 = __builtin_bit_cast(u64x2, r2), q3 = __builtin_bit_cast(u64x2, r3); \
      u64x2 q4 = __builtin_bit_cast(u64x2, r4), q5 = __builtin_bit_cast(u64x2, r5); \
      u64x2 q6 = __builtin_bit_cast(u64x2, r6), q7 = __builtin_bit_cast(u64x2, r7); \
      unsigned long long bad =                                                \
          stale64(q0.x) | stale64(q0.y) | stale64(q1.x) | stale64(q1.y) |     \
          stale64(q2.x) | stale64(q2.y) | stale64(q3.x) | stale64(q3.y) |     \
          stale64(q4.x) | stale64(q4.y) | stale64(q5.x) | stale64(q5.y) |     \
          stale64(q6.x) | stale64(q6.y) | stale64(q7.x) | stale64(q7.y);      \
      if (!bad) break;                                                        \
    }                                                                         \
    *(i32x4*)&img[widx[0]] = r0;                                              \
    *(i32x4*)&img[widx[1]] = r1;                                              \
    *(i32x4*)&img[widx[2]] = r2;                                              \
    *(i32x4*)&img[widx[3]] = r3;                                              \
    *(i32x4*)&img[widx[4]] = r4;                                              \
    *(i32x4*)&img[widx[5]] = r5;                                              \
    *(i32x4*)&img[widx[6]] = r6;                                              \
    *(i32x4*)&img[widx[7]] = r7;                                              \
  } while (0)

// ---- fused 2-layer pipelined LSTM (EXACT R1 -- proven 1815us) ----
// grid = 192 WGs x 512 threads, all resident (1 WG/CU), no inter-group cycles.
//   WGs   0..63 : layer-0 recurrence. WG owns 128 gate-rows x 16 batches.
//   WGs 64..191 : layer-1. WG owns 64 gate-rows x 16 batches; waves 0-3 hold
//                 Whh1 (consume h1[t-1] image), waves 4-7 hold Wih1 (consume
//                 h0[t] image); partial gate sums meet in an LDS red buffer.
// hs is pre-filled with sentinel 0x7F7F; the packed 8B agent-scope h store IS
// the readiness signal (one hop: data write == signal; 8B atomic arrival unit
// == verification unit). Per-step rendezvous barriers keep waves in lockstep,
// which empirically minimizes poll rounds (R3/R4 lesson).
__global__ __launch_bounds__(512, 1) void lstm_fused(
    const short* __restrict__ gx0, const short* __restrict__ whh0,
    const float* __restrict__ b0p, const short* __restrict__ wih1,
    const short* __restrict__ whh1, const float* __restrict__ b1p,
    short* __restrict__ hs0, short* __restrict__ hs1,
    float* __restrict__ out, float* __restrict__ hn, float* __restrict__ cn) {
  const int tid = threadIdx.x;
  const int lane = tid & 63, w = tid >> 6;
  const int fr = lane & 15, fq = lane >> 4;

  __shared__ __align__(16) short img[32 * 1024];   // L0: first 16K shorts; L1: mw halves
  __shared__ __align__(16) float red[4 * 64 * 4];  // L1 only: 4KB k-partial exchange

  if (blockIdx.x < 64) {
    // ================= layer 0: 128 gate-rows x 16 batches =================
    const int rg = (int)blockIdx.x >> 1, bg = (int)blockIdx.x & 1;
    const int n_base = rg * 128 + w * 16;
    const int b = bg * 16 + fr;
    const int jb = rg * 32 + w * 4;   // wave's output j-quad base
    const int j = jb + fq;
    const int sw = fr & 7;

    const short* arow = whh0 + (size_t)(n_base + fr) * 1024 + fq * 8;
    short8 wreg[32];
#pragma unroll
    for (int kk = 0; kk < 32; kk++) wreg[kk] = *(const short8*)(arow + kk * 32);

    float bia[4];
#pragma unroll
    for (int r = 0; r < 4; r++) bia[r] = b0p[n_base + fq * 4 + r];

    // stage: 2048 16B chunks of the 32KB half-image over 512 threads (4 each)
    unsigned int soff[4];
    int widx[4];
#pragma unroll
    for (int i = 0; i < 4; i++) {
      int ch = tid + i * 512;
      soff[i] = (unsigned int)ch * 16;
      int bb = ch >> 7, cc = ch & 127;
      widx[i] = bb * 1024 + ((cc ^ (bb & 7)) << 3);
    }

    float cell = 0.f;
    for (int t = 0; t < 512; ++t) {
      unsigned long long gq = *(const unsigned long long*)(
          gx0 + (size_t)t * 131072 + (size_t)b * 4096 + n_base + fq * 4);

      if (t > 0) {
        const short* hbp = hs0 + (size_t)(t - 1) * 32768 + bg * 16384;
        i32x4 r0, r1, r2, r3;
        while (true) {
          asm volatile(
              "global_load_dwordx4 %0, %4, %8 sc0 sc1\n\t"
              "global_load_dwordx4 %1, %5, %8 sc0 sc1\n\t"
              "global_load_dwordx4 %2, %6, %8 sc0 sc1\n\t"
              "global_load_dwordx4 %3, %7, %8 sc0 sc1\n\t"
              "s_waitcnt vmcnt(0)"
              : "=&v"(r0), "=&v"(r1), "=&v"(r2), "=&v"(r3)
              : "v"(soff[0]), "v"(soff[1]), "v"(soff[2]), "v"(soff[3]),
                "s"(hbp)
              : "memory");
          u64x2 q0 = __builtin_bit_cast(u64x2, r0);
          u64x2 q1 = __builtin_bit_cast(u64x2, r1);
          u64x2 q2 = __builtin_bit_cast(u64x2, r2);
          u64x2 q3 = __builtin_bit_cast(u64x2, r3);
          unsigned long long bad =
              stale64(q0.x) | stale64(q0.y) | stale64(q1.x) | stale64(q1.y) |
              stale64(q2.x) | stale64(q2.y) | stale64(q3.x) | stale64(q3.y);
          if (!bad) break;
        }
        *(i32x4*)&img[widx[0]] = r0;
        *(i32x4*)&img[widx[1]] = r1;
        *(i32x4*)&img[widx[2]] = r2;
        *(i32x4*)&img[widx[3]] = r3;
      }
      __syncthreads();  // LDS h-image ready

      f32x4 a0 = (f32x4){0.f,0.f,0.f,0.f}, a1 = (f32x4){0.f,0.f,0.f,0.f};
      f32x4 a2 = (f32x4){0.f,0.f,0.f,0.f}, a3 = (f32x4){0.f,0.f,0.f,0.f};
      if (t > 0) {
#pragma unroll
        for (int m = 0; m < 8; m++) {
          const int chb = fq + m * 16;
          short8 bv0 = *(const short8*)&img[fr * 1024 + (((chb + 0) ^ sw) << 3)];
          short8 bv1 = *(const short8*)&img[fr * 1024 + (((chb + 4) ^ sw) << 3)];
          short8 bv2 = *(const short8*)&img[fr * 1024 + (((chb + 8) ^ sw) << 3)];
          short8 bv3 = *(const short8*)&img[fr * 1024 + (((chb + 12) ^ sw) << 3)];
          a0 = __builtin_amdgcn_mfma_f32_16x16x32_bf16(wreg[4 * m + 0], bv0, a0, 0, 0, 0);
          a1 = __builtin_amdgcn_mfma_f32_16x16x32_bf16(wreg[4 * m + 1], bv1, a1, 0, 0, 0);
          a2 = __builtin_amdgcn_mfma_f32_16x16x32_bf16(wreg[4 * m + 2], bv2, a2, 0, 0, 0);
          a3 = __builtin_amdgcn_mfma_f32_16x16x32_bf16(wreg[4 * m + 3], bv3, a3, 0, 0, 0);
        }
      }

      float pre0 = (a0[0] + a1[0]) + (a2[0] + a3[0]) + bf2f((unsigned short)(gq & 0xFFFF)) + bia[0];
      float pre1 = (a0[1] + a1[1]) + (a2[1] + a3[1]) + bf2f((unsigned short)((gq >> 16) & 0xFFFF)) + bia[1];
      float pre2 = (a0[2] + a1[2]) + (a2[2] + a3[2]) + bf2f((unsigned short)((gq >> 32) & 0xFFFF)) + bia[2];
      float pre3 = (a0[3] + a1[3]) + (a2[3] + a3[3]) + bf2f((unsigned short)((gq >> 48) & 0xFFFF)) + bia[3];

      float iv = 1.f / (1.f + __expf(-pre0));
      float fv = 1.f / (1.f + __expf(-pre1));
      float gv = 2.f / (1.f + __expf(-2.f * pre2)) - 1.f;
      float ov = 1.f / (1.f + __expf(-pre3));
      cell = fv * cell + iv * gv;
      float h = ov * (2.f / (1.f + __expf(-2.f * cell)) - 1.f);

      // pack 4 gate-columns (lanes fq=0..3, same b) into one 8B coherent store
      unsigned int hu = (unsigned int)f2bf(h);
      unsigned int v1 = __shfl(hu, fr + 16);
      unsigned int v2 = __shfl(hu, fr + 32);
      unsigned int v3 = __shfl(hu, fr + 48);
      if (fq == 0) {
        unsigned long long pk = (unsigned long long)hu |
                                ((unsigned long long)v1 << 16) |
                                ((unsigned long long)v2 << 32) |
                                ((unsigned long long)v3 << 48);
        __hip_atomic_store(
            (unsigned long long*)(hs0 + (size_t)t * 32768 + (size_t)b * 1024 + jb),
            pk, __ATOMIC_RELAXED, __HIP_MEMORY_SCOPE_AGENT);
      }
      if (t == 511) {
        hn[b * 1024 + j] = h;
        cn[b * 1024 + j] = cell;
        break;
      }
      __syncthreads();  // protect LDS image until all waves' k-loop reads done
    }
  } else {
    // ================= layer 1: 64 gate-rows x 16 batches, dual-matrix =====
    const int idx = (int)blockIdx.x - 64;
    const int rg = idx >> 1, bg = idx & 1;
    const int wn = w & 3, mw = w >> 2;        // mw=0: Whh1/h1, mw=1: Wih1/h0
    const int n_base = rg * 64 + wn * 16;
    const int b = bg * 16 + fr;
    const int jb = rg * 16 + wn * 4;
    const int j = jb + fq;
    const int sw = fr & 7;
    const int ib = mw << 14;                  // LDS image half (shorts)

    const short* wsrc = mw ? wih1 : whh1;
    const short* arow = wsrc + (size_t)(n_base + fr) * 1024 + fq * 8;
    short8 wreg[32];
#pragma unroll
    for (int kk = 0; kk < 32; kk++) wreg[kk] = *(const short8*)(arow + kk * 32);

    float bia[4];
#pragma unroll
    for (int r = 0; r < 4; r++) bia[r] = b1p[n_base + fq * 4 + r];

    // each 256-thread half stages its own 32KB image: 8 chunks/thread
    const int lt = tid & 255;
    unsigned int soff[8];
    int widx[8];
#pragma unroll
    for (int i = 0; i < 8; i++) {
      int ch = lt + i * 256;
      soff[i] = (unsigned int)ch * 16;
      int bb = ch >> 7, cc = ch & 127;
      widx[i] = ib + bb * 1024 + ((cc ^ (bb & 7)) << 3);
    }

    float cell = 0.f;
    for (int t = 0; t < 512; ++t) {
      if (mw) {
        const short* hbp = hs0 + (size_t)t * 32768 + bg * 16384;
        POLL8(hbp);
      } else if (t > 0) {
        const short* hbp = hs1 + (size_t)(t - 1) * 32768 + bg * 16384;
        POLL8(hbp);
      }
      __syncthreads();  // #1: both images staged

      f32x4 a0 = (f32x4){0.f,0.f,0.f,0.f}, a1 = (f32x4){0.f,0.f,0.f,0.f};
      f32x4 a2 = (f32x4){0.f,0.f,0.f,0.f}, a3 = (f32x4){0.f,0.f,0.f,0.f};
      if (mw || t > 0) {
#pragma unroll
        for (int m = 0; m < 8; m++) {
          const int chb = fq + m * 16;
          short8 bv0 = *(const short8*)&img[ib + fr * 1024 + (((chb + 0) ^ sw) << 3)];
          short8 bv1 = *(const short8*)&img[ib + fr * 1024 + (((chb + 4) ^ sw) << 3)];
          short8 bv2 = *(const short8*)&img[ib + fr * 1024 + (((chb + 8) ^ sw) << 3)];
          short8 bv3 = *(const short8*)&img[ib + fr * 1024 + (((chb + 12) ^ sw) << 3)];
          a0 = __builtin_amdgcn_mfma_f32_16x16x32_bf16(wreg[4 * m + 0], bv0, a0, 0, 0, 0);
          a1 = __builtin_amdgcn_mfma_f32_16x16x32_bf16(wreg[4 * m + 1], bv1, a1, 0, 0, 0);
          a2 = __builtin_amdgcn_mfma_f32_16x16x32_bf16(wreg[4 * m + 2], bv2, a2, 0, 0, 0);
          a3 = __builtin_amdgcn_mfma_f32_16x16x32_bf16(wreg[4 * m + 3], bv3, a3, 0, 0, 0);
        }
      }
      f32x4 s4 = (a0 + a1) + (a2 + a3);
      if (mw) *(f32x4*)&red[(wn * 64 + lane) * 4] = s4;
      __syncthreads();  // #2: Wih1 partials visible

      if (!mw) {
        const f32x4 o4 = *(const f32x4*)&red[(wn * 64 + lane) * 4];
        float pre0 = s4[0] + o4[0] + bia[0];
        float pre1 = s4[1] + o4[1] + bia[1];
        float pre2 = s4[2] + o4[2] + bia[2];
        float pre3 = s4[3] + o4[3] + bia[3];

        float iv = 1.f / (1.f + __expf(-pre0));
        float fv = 1.f / (1.f + __expf(-pre1));
        float gv = 2.f / (1.f + __expf(-2.f * pre2)) - 1.f;
        float ov = 1.f / (1.f + __expf(-pre3));
        cell = fv * cell + iv * gv;
        float h = ov * (2.f / (1.f + __expf(-2.f * cell)) - 1.f);

        unsigned int hu = (unsigned int)f2bf(h);
        unsigned int v1 = __shfl(hu, fr + 16);
        unsigned int v2 = __shfl(hu, fr + 32);
        unsigned int v3 = __shfl(hu, fr + 48);
        if (fq == 0) {
          unsigned long long pk = (unsigned long long)hu |
                                  ((unsigned long long)v1 << 16) |
                                  ((unsigned long long)v2 << 32) |
                                  ((unsigned long long)v3 << 48);
          __hip_atomic_store(
              (unsigned long long*)(hs1 + (size_t)t * 32768 + (size_t)b * 1024 + jb),
              pk, __ATOMIC_RELAXED, __HIP_MEMORY_SCOPE_AGENT);
        }
        out[(size_t)b * 524288 + (size_t)t * 1024 + j] = h;
        if (t == 511) {
          hn[32768 + b * 1024 + j] = h;
          cn[32768 + b * 1024 + j] = cell;
        }
      }
      if (t == 511) break;
      __syncthreads();  // #3: protect LDS image/red until all reads done
    }
  }
}

extern "C" void kernel_launch(void* const* d_in, const int* in_sizes, int n_in,
                              void* d_out, int out_size, void* d_ws, size_t ws_size,
                              hipStream_t stream) {
  const float* x    = (const float*)d_in[0];
  const float* Wih0 = (const float*)d_in[1];
  const float* b0   = (const float*)d_in[2];
  const float* Whh0 = (const float*)d_in[3];
  const float* Wih1 = (const float*)d_in[4];
  const float* b1   = (const float*)d_in[5];
  const float* Whh1 = (const float*)d_in[6];

  float* out = (float*)d_out;          // [32][512][1024]
  float* hn  = out + 16777216;         // [2][32][1024]
  float* cn  = hn + 65536;

  char* ws = (char*)d_ws;
  size_t off = 0;
  auto carve = [&](size_t bytes) {
    char* p = ws + off;
    off += (bytes + 255) & ~(size_t)255;
    return p;
  };
  short* wih0p = (short*)carve(4096ull * 1024 * 2);
  short* whh0p = (short*)carve(4096ull * 1024 * 2);
  short* wih1p = (short*)carve(4096ull * 1024 * 2);
  short* whh1p = (short*)carve(4096ull * 1024 * 2);
  float* b0p   = (float*)carve(4096 * 4);
  float* b1p   = (float*)carve(4096 * 4);
  short* gx    = (short*)carve(512ull * 4096 * 32 * 2);  // [t][b][n] layer-0 only
  short* hs0   = (short*)carve(16384ull * 1024 * 2);
  short* hs1   = (short*)carve(16384ull * 1024 * 2);

  // phase 0: weight/bias conversions + sentinel fills
  hipLaunchKernelGGL(cvt_w_kernel, dim3(1024), dim3(256), 0, stream, Wih0, wih0p);
  hipLaunchKernelGGL(cvt_w_kernel, dim3(1024), dim3(256), 0, stream, Whh0, whh0p);
  hipLaunchKernelGGL(cvt_w_kernel, dim3(1024), dim3(256), 0, stream, Wih1, wih1p);
  hipLaunchKernelGGL(cvt_w_kernel, dim3(1024), dim3(256), 0, stream, Whh1, whh1p);
  hipLaunchKernelGGL(cvt_b_kernel, dim3(16), dim3(256), 0, stream, b0, b0p);
  hipLaunchKernelGGL(cvt_b_kernel, dim3(16), dim3(256), 0, stream, b1, b1p);
  (void)hipMemsetAsync(hs0, 0x7F, 16384ull * 1024 * 2, stream);
  (void)hipMemsetAsync(hs1, 0x7F, 16384ull * 1024 * 2, stream);

  // layer-0 input GEMM with fused x->bf16 conversion (runs serially BEFORE
  // the recurrence: R6 showed concurrent bulk GEMM traffic slows the
  // latency-critical handoff chain by ~55%)
  hipLaunchKernelGGL(gemm_btx, dim3(32, 128), dim3(256), 0, stream,
                     (const short*)wih0p, x, gx);

  // fused, pipelined 2-layer recurrence: 64 layer-0 WGs + 128 layer-1 WGs
  hipLaunchKernelGGL(lstm_fused, dim3(192), dim3(512), 0, stream,
                     (const short*)gx, (const short*)whh0p, (const float*)b0p,
                     (const short*)wih1p, (const short*)whh1p, (const float*)b1p,
                     hs0, hs1, out, hn, cn);
}